// Round 4
// baseline (421.282 us; speedup 1.0000x reference)
//
#include <hip/hip_runtime.h>
#include <stdint.h>

#define NB 8
#define NC 256
#define NE 128
#define NHW 4096

typedef __bf16 v8bf __attribute__((ext_vector_type(8)));
typedef float v4f __attribute__((ext_vector_type(4)));
typedef float v16f __attribute__((ext_vector_type(16)));
typedef unsigned int v4u __attribute__((ext_vector_type(4)));

typedef unsigned int __attribute__((address_space(1))) uint_g;
typedef unsigned int __attribute__((address_space(3))) uint_l;

#if __has_builtin(__builtin_amdgcn_exp2f)
#define EXP2F(x) __builtin_amdgcn_exp2f(x)
#else
#define EXP2F(x) exp2f(x)
#endif

// LDS-only barrier: drains lgkmcnt but NOT vmcnt (global prefetch/DMA stays in flight)
#define BARRIER_LDS() asm volatile("s_waitcnt lgkmcnt(0)\n\ts_barrier" ::: "memory")
#define WAIT_VM0()    asm volatile("s_waitcnt vmcnt(0)" ::: "memory")

// async global->LDS DMA, 16B per lane: LDS dst = uniform base + lane*16
__device__ __forceinline__ void dma16(const unsigned short* g, unsigned short* l) {
    __builtin_amdgcn_global_load_lds((const uint_g*)g, (uint_l*)l, 16, 0, 0);
}

// fp32 -> bf16 round-to-nearest-even
__device__ __forceinline__ unsigned short f2bf(float x) {
    union { float f; unsigned int u; } v; v.f = x;
    unsigned int r = v.u + 0x7fffu + ((v.u >> 16) & 1u);
    return (unsigned short)(r >> 16);
}

// pack two fp32 -> bf16x2, round-half-up (P in (0,1], R4-verified accuracy)
__device__ __forceinline__ unsigned int pack_bf2_ru(float a, float b) {
    union { float f; unsigned int u; } va, vb; va.f = a; vb.f = b;
    return ((va.u + 0x8000u) >> 16) | ((vb.u + 0x8000u) & 0xffff0000u);
}

// ---------------- K0: cast weights. Wbf[e][c], e<128 = w_theta*(scale*log2e), e>=128 = w_phi
__global__ __launch_bounds__(256) void cast_w_kernel(const float* __restrict__ wt,
                                                     const float* __restrict__ wp,
                                                     unsigned short* __restrict__ Wbf) {
    int i = blockIdx.x * 256 + threadIdx.x;
    const float QS = 0.08838834764831845f * 1.4426950408889634f;
    float v = (i < 32768) ? wt[i] * QS : wp[i - 32768];
    Wbf[i] = f2bf(v);
}

// ---------------- K1: projection (+ fused V cast). K is stored PRE-SWIZZLED
// (16B unit u at position u ^ (row&15) within each row) so attn's LDS DMA copy
// is read conflict-free with the R5-verified fragment pattern. Q unswizzled.
__global__ __launch_bounds__(256, 2) void proj_kernel(const float* __restrict__ l,
                                                      const unsigned short* __restrict__ Wbf,
                                                      unsigned short* __restrict__ Qbf,
                                                      unsigned short* __restrict__ Kbf,
                                                      unsigned short* __restrict__ Vbf) {
    __shared__ __align__(16) unsigned short A[64][264];
    __shared__ __align__(16) unsigned short Ost[2][32][136];
    const int tid = threadIdx.x;
    const int b = blockIdx.x & 7;
    const int qt = (blockIdx.x >> 3) << 6;
    const float* lb = l + ((size_t)b * NC * NHW + qt);

    for (int s = 0; s < 16; ++s) {
        int f = tid + s * 256;
        int c = f >> 4, j = f & 15;
        float4 v = *(const float4*)(lb + (size_t)c * NHW + j * 4);
        ushort4 o4;
        o4.x = f2bf(v.x); o4.y = f2bf(v.y); o4.z = f2bf(v.z); o4.w = f2bf(v.w);
        A[j * 4 + 0][c] = o4.x;
        A[j * 4 + 1][c] = o4.y;
        A[j * 4 + 2][c] = o4.z;
        A[j * 4 + 3][c] = o4.w;
        *(ushort4*)(Vbf + (size_t)b * NC * NHW + (size_t)c * NHW + qt + j * 4) = o4;
    }
    __syncthreads();

    const int w = tid >> 6, L = tid & 63;
    const int l15 = L & 15, q4 = L >> 4;
    const v4f vz = {0.f, 0.f, 0.f, 0.f};
    v4f acc[4][4];
    for (int mt = 0; mt < 4; ++mt)
        for (int nt = 0; nt < 4; ++nt) acc[mt][nt] = vz;

    for (int kf = 0; kf < 8; ++kf) {
        int kc = kf * 32 + q4 * 8;
        v8bf a[4], bb[4];
        for (int mt = 0; mt < 4; ++mt)
            a[mt] = *(const v8bf*)&A[mt * 16 + l15][kc];
        for (int nt = 0; nt < 4; ++nt)
            bb[nt] = *(const v8bf*)(Wbf + (w * 64 + nt * 16 + l15) * 256 + kc);
        for (int mt = 0; mt < 4; ++mt)
            for (int nt = 0; nt < 4; ++nt)
                acc[mt][nt] = __builtin_amdgcn_mfma_f32_16x16x32_bf16(a[mt], bb[nt], acc[mt][nt], 0, 0, 0);
    }

    const int side = w >> 1;
    const int ebase = (w & 1) * 64;
#pragma unroll
    for (int ph = 0; ph < 2; ++ph) {
        __syncthreads();
#pragma unroll
        for (int mh = 0; mh < 2; ++mh) {
            int mt = ph * 2 + mh;
#pragma unroll
            for (int nt = 0; nt < 4; ++nt)
#pragma unroll
                for (int r = 0; r < 4; ++r) {
                    int q32 = mh * 16 + q4 * 4 + r;
                    Ost[side][q32][ebase + nt * 16 + l15] = f2bf(acc[mt][nt][r]);
                }
        }
        __syncthreads();
#pragma unroll
        for (int s = 0; s < 4; ++s) {
            int idx = tid + s * 256;
            int sd = idx >> 9, rem = idx & 511;
            int r32 = rem >> 4, c8 = rem & 15;
            unsigned short* dst = sd ? Kbf : Qbf;
            int c8s = sd ? (c8 ^ (r32 & 15)) : c8;   // pre-swizzle K only
            *(uint4*)(dst + ((size_t)b * NHW + qt + ph * 32 + r32) * NE + c8s * 8) =
                *(const uint4*)&Ost[sd][r32][c8 * 8];
        }
    }
}

// ---------------- K2: flash attention, HOMOGENEOUS waves (R4 redesign).
// R1/R3 post-mortems: P/C wave specialization forces the UNION of producer
// state (s-regs) and consumer state (o[128]) in static register allocation ->
// any added pipelining state spills (R3: WRITE_SIZE 39->308 MB).  Fix: all 8
// waves identical.  Wave (ch=w>>2, qs=w&3) owns O^T[128c x 32q] (o[4]=64 regs).
// Per round (k-tile 64): QK S^T[64k x 32q] (16 MFMA, A=K from DMA'd LDS,
// R5-verified swizzled reads; B=Q regs) -> in-reg softmax -> in-reg P^T
// B-frags (R3/R8-verified lane^32 exchange) -> PV (16 MFMA, A=V global-direct
// frags, B=own P frags).  No Pu LDS round-trip, no P handoff barrier, no
// 65th round, no lsum LDS (each wave sees all k for its q-cols).
// Cost: QK+softmax duplicated across the 2 ch-waves per qs (+33% matrix
// demand), V read 4x-redundantly from same-XCD L2.  Register peak ~220 < 256.
// Per SIMD per round: 2 waves x 32 MFMA = 2048 matrix cyc; serial chain
// QK->SM->PV ~1500 cyc sits under it.
// LDS: Ku dbuf 32K only.
__global__ __launch_bounds__(512, 2) void attn_kernel(const unsigned short* __restrict__ Qbf,
                                                      const unsigned short* __restrict__ Kbf,
                                                      const unsigned short* __restrict__ Vbf,
                                                      float* __restrict__ out) {
    __shared__ __align__(16) unsigned short KuS[2 * 8192];   // 2 x 16KB swizzled K tiles

    const int tid = threadIdx.x;
    const int b = blockIdx.x & 7;                            // batch -> XCD affinity
    const int q128 = (blockIdx.x >> 3) << 7;
    const int w = tid >> 6;                                  // wave 0-7 -> SIMD w&3
    const int L = tid & 63;
    const int l31 = L & 31, hi = L >> 5;
    const int x15 = l31 & 15;
    const int qs = w & 3;                                    // q-sub: 32 rows at q128+qs*32
    const int ch = w >> 2;                                   // c-half: 128 ch at ch*128

    const unsigned short* Kb = Kbf + (size_t)b * NHW * NE;
    const unsigned short* Vb = Vbf + (size_t)b * NC * NHW;

    v16f o[4];                                               // O^T acc [cb], 64 regs
#pragma unroll
    for (int cb = 0; cb < 4; ++cb)
#pragma unroll
        for (int r = 0; r < 16; ++r) o[cb][r] = 0.f;
    float lacc = 0.f;                                        // row-sum partial (q-col l31)

    // Q B-frags for this wave's 32 q-rows
    v8bf bq[8];
    const unsigned short* qrow = Qbf + ((size_t)b * NHW + q128 + qs * 32 + l31) * NE + hi * 8;
#pragma unroll
    for (int ef = 0; ef < 8; ++ef)
        bq[ef] = *(const v8bf*)(qrow + ef * 16);

    // V A-frag row bases for 4 c-blocks (R6-verified addressing pattern)
    const unsigned short* vb[4];
#pragma unroll
    for (int cb = 0; cb < 4; ++cb)
        vb[cb] = Vb + (size_t)(ch * 128 + cb * 32 + l31) * NHW + hi * 8;

    // stage K tile 0 into buf 0 (16 x 1KB chunks over 8 waves)
#pragma unroll
    for (int jj = 0; jj < 2; ++jj) {
        int j = w * 2 + jj;
        dma16(Kb + (size_t)j * 512 + L * 8, KuS + j * 512);
    }
    WAIT_VM0();
    BARRIER_LDS();

    for (int it = 0; it < 64; ++it) {
        const int buf = it & 1;
        // V A-frags for this round (global, same-XCD L2; used at round end -> slack)
        v8bf av[4][4];
        const size_t kc0 = (size_t)it * 64;
#pragma unroll
        for (int cb = 0; cb < 4; ++cb)
#pragma unroll
            for (int kf = 0; kf < 4; ++kf)
                av[cb][kf] = *(const v8bf*)(vb[cb] + kc0 + kf * 16);
        // DMA next K tile into other buf (tile there is dead since last round's barrier);
        // wrapped index keeps round 63 uniform (dead 16KB prefetch, never read)
        const size_t ktn = (size_t)((it + 1) & 63) * 64;
#pragma unroll
        for (int jj = 0; jj < 2; ++jj) {
            int j = w * 2 + jj;
            dma16(Kb + ktn * NE + (size_t)j * 512 + L * 8, KuS + ((it + 1) & 1) * 8192 + j * 512);
        }
        // QK + softmax + P^T frags, per 32-row k-slab
        const unsigned short* kub = KuS + buf * 8192;
        v8bf bp[4];
#pragma unroll
        for (int kt = 0; kt < 2; ++kt) {
            v16f sa, sb;
#pragma unroll
            for (int r = 0; r < 16; ++r) { sa[r] = 0.f; sb[r] = 0.f; }
            const unsigned short* krow = kub + (kt * 32 + l31) * 128;
#pragma unroll
            for (int ef = 0; ef < 4; ++ef) {
                v8bf ak0 = *(const v8bf*)(krow + (((2 * ef + hi) ^ x15) * 8));
                v8bf ak1 = *(const v8bf*)(krow + (((2 * (ef + 4) + hi) ^ x15) * 8));
                sa = __builtin_amdgcn_mfma_f32_32x32x16_bf16(ak0, bq[ef], sa, 0, 0, 0);
                sb = __builtin_amdgcn_mfma_f32_32x32x16_bf16(ak1, bq[ef + 4], sb, 0, 0, 0);
            }
            // softmax (scale*log2e folded into Q); lane owns q-col l31
            float p[16];
#pragma unroll
            for (int r = 0; r < 16; ++r) p[r] = EXP2F(sa[r] + sb[r]);
#pragma unroll
            for (int r = 0; r < 16; ++r) lacc += p[r];
            // P^T B-frags in regs (R3/R8-verified exchange)
            unsigned int pk[8], px[8];
#pragma unroll
            for (int t = 0; t < 8; ++t) pk[t] = pack_bf2_ru(p[2 * t], p[2 * t + 1]);
#pragma unroll
            for (int t = 0; t < 8; ++t) px[t] = (unsigned int)__shfl_xor((int)pk[t], 32);
            union { v4u u; v8bf bb; } f0, f1;
            if (hi == 0) {
                f0.u = (v4u){pk[0], pk[1], px[0], px[1]};
                f1.u = (v4u){pk[4], pk[5], px[4], px[5]};
            } else {
                f0.u = (v4u){px[2], px[3], pk[2], pk[3]};
                f1.u = (v4u){px[6], px[7], pk[6], pk[7]};
            }
            bp[kt * 2 + 0] = f0.bb;
            bp[kt * 2 + 1] = f1.bb;
        }
        // PV: O^T[128c x 32q] += V x P^T  (own frags; compiler inserts av vmcnt wait)
#pragma unroll
        for (int cb = 0; cb < 4; ++cb)
#pragma unroll
            for (int kf = 0; kf < 4; ++kf)
                o[cb] = __builtin_amdgcn_mfma_f32_32x32x16_bf16(av[cb][kf], bp[kf], o[cb], 0, 0, 0);
        WAIT_VM0();                                          // K DMA(i+1) landed
        BARRIER_LDS();
    }

    // epilogue: in-reg row-sum finalize (no LDS handoff)
    float tot = lacc + __shfl_xor(lacc, 32);
    float inv = 1.0f / tot;
    // store: O^T C/D lane = q-col -> coalesced dwords
    float* ob = out + (size_t)b * NC * NHW + q128 + qs * 32 + l31;
#pragma unroll
    for (int cb = 0; cb < 4; ++cb)
#pragma unroll
        for (int r = 0; r < 16; ++r) {
            int c = ch * 128 + cb * 32 + (r & 3) + 8 * (r >> 2) + 4 * hi;
            ob[(size_t)c * NHW] = o[cb][r] * inv;
        }
}

extern "C" void kernel_launch(void* const* d_in, const int* in_sizes, int n_in,
                              void* d_out, int out_size, void* d_ws, size_t ws_size,
                              hipStream_t stream) {
    const float* l  = (const float*)d_in[0];
    const float* wt = (const float*)d_in[1];
    const float* wp = (const float*)d_in[2];
    float* out = (float*)d_out;

    char* ws = (char*)d_ws;
    unsigned short* Wbf = (unsigned short*)ws;                          // 131072 B
    unsigned short* Qbf = (unsigned short*)(ws + 131072);               // 8 MB
    unsigned short* Kbf = (unsigned short*)(ws + 131072 + 8388608);     // 8 MB (pre-swizzled)
    unsigned short* Vbf = (unsigned short*)(ws + 131072 + 16777216);    // 16 MB

    hipLaunchKernelGGL(cast_w_kernel, dim3(256), dim3(256), 0, stream, wt, wp, Wbf);
    hipLaunchKernelGGL(proj_kernel,   dim3(512), dim3(256), 0, stream, l, Wbf, Qbf, Kbf, Vbf);
    hipLaunchKernelGGL(attn_kernel,   dim3(256), dim3(512), 0, stream, Qbf, Kbf, Vbf, out);
}

// Round 5
// 353.998 us; speedup vs baseline: 1.1901x; 1.1901x over previous
//
#include <hip/hip_runtime.h>
#include <stdint.h>

#define NB 8
#define NC 256
#define NE 128
#define NHW 4096

typedef __bf16 v8bf __attribute__((ext_vector_type(8)));
typedef float v4f __attribute__((ext_vector_type(4)));
typedef float v16f __attribute__((ext_vector_type(16)));
typedef unsigned int v4u __attribute__((ext_vector_type(4)));

typedef unsigned int __attribute__((address_space(1))) uint_g;
typedef unsigned int __attribute__((address_space(3))) uint_l;

#if __has_builtin(__builtin_amdgcn_exp2f)
#define EXP2F(x) __builtin_amdgcn_exp2f(x)
#else
#define EXP2F(x) exp2f(x)
#endif

// LDS-only barrier: drains lgkmcnt but NOT vmcnt (global prefetch/DMA stays in flight)
#define BARRIER_LDS() asm volatile("s_waitcnt lgkmcnt(0)\n\ts_barrier" ::: "memory")
#define WAIT_VM0()    asm volatile("s_waitcnt vmcnt(0)" ::: "memory")

// gfx950 cross-half exchange: swaps hi 32 lanes of a with lo 32 lanes of b.
// After: a[l<32]=a(l), a[l>=32]=b(l-32), b[l<32]=a(l+32), b[l>=32]=b(l).
#define PERMSWAP32(a, b) asm volatile("v_permlane32_swap_b32 %0, %1" : "+v"(a), "+v"(b))

// async global->LDS DMA, 16B per lane: LDS dst = uniform base + lane*16
__device__ __forceinline__ void dma16(const unsigned short* g, unsigned short* l) {
    __builtin_amdgcn_global_load_lds((const uint_g*)g, (uint_l*)l, 16, 0, 0);
}

// fp32 -> bf16 round-to-nearest-even
__device__ __forceinline__ unsigned short f2bf(float x) {
    union { float f; unsigned int u; } v; v.f = x;
    unsigned int r = v.u + 0x7fffu + ((v.u >> 16) & 1u);
    return (unsigned short)(r >> 16);
}

// pack two fp32 -> bf16x2, round-half-up (P in (0,1], R4-verified accuracy)
__device__ __forceinline__ unsigned int pack_bf2_ru(float a, float b) {
    union { float f; unsigned int u; } va, vb; va.f = a; vb.f = b;
    return ((va.u + 0x8000u) >> 16) | ((vb.u + 0x8000u) & 0xffff0000u);
}

// ---------------- K0: cast weights. Wbf[e][c], e<128 = w_theta*(scale*log2e), e>=128 = w_phi
__global__ __launch_bounds__(256) void cast_w_kernel(const float* __restrict__ wt,
                                                     const float* __restrict__ wp,
                                                     unsigned short* __restrict__ Wbf) {
    int i = blockIdx.x * 256 + threadIdx.x;
    const float QS = 0.08838834764831845f * 1.4426950408889634f;
    float v = (i < 32768) ? wt[i] * QS : wp[i - 32768];
    Wbf[i] = f2bf(v);
}

// ---------------- K1: projection (+ fused V cast). K is stored PRE-SWIZZLED
// (16B unit u at position u ^ (row&15) within each row) so attn's LDS DMA copy
// is read conflict-free with the R5-verified fragment pattern. Q unswizzled.
__global__ __launch_bounds__(256, 2) void proj_kernel(const float* __restrict__ l,
                                                      const unsigned short* __restrict__ Wbf,
                                                      unsigned short* __restrict__ Qbf,
                                                      unsigned short* __restrict__ Kbf,
                                                      unsigned short* __restrict__ Vbf) {
    __shared__ __align__(16) unsigned short A[64][264];
    __shared__ __align__(16) unsigned short Ost[2][32][136];
    const int tid = threadIdx.x;
    const int b = blockIdx.x & 7;
    const int qt = (blockIdx.x >> 3) << 6;
    const float* lb = l + ((size_t)b * NC * NHW + qt);

    for (int s = 0; s < 16; ++s) {
        int f = tid + s * 256;
        int c = f >> 4, j = f & 15;
        float4 v = *(const float4*)(lb + (size_t)c * NHW + j * 4);
        ushort4 o4;
        o4.x = f2bf(v.x); o4.y = f2bf(v.y); o4.z = f2bf(v.z); o4.w = f2bf(v.w);
        A[j * 4 + 0][c] = o4.x;
        A[j * 4 + 1][c] = o4.y;
        A[j * 4 + 2][c] = o4.z;
        A[j * 4 + 3][c] = o4.w;
        *(ushort4*)(Vbf + (size_t)b * NC * NHW + (size_t)c * NHW + qt + j * 4) = o4;
    }
    __syncthreads();

    const int w = tid >> 6, L = tid & 63;
    const int l15 = L & 15, q4 = L >> 4;
    const v4f vz = {0.f, 0.f, 0.f, 0.f};
    v4f acc[4][4];
    for (int mt = 0; mt < 4; ++mt)
        for (int nt = 0; nt < 4; ++nt) acc[mt][nt] = vz;

    for (int kf = 0; kf < 8; ++kf) {
        int kc = kf * 32 + q4 * 8;
        v8bf a[4], bb[4];
        for (int mt = 0; mt < 4; ++mt)
            a[mt] = *(const v8bf*)&A[mt * 16 + l15][kc];
        for (int nt = 0; nt < 4; ++nt)
            bb[nt] = *(const v8bf*)(Wbf + (w * 64 + nt * 16 + l15) * 256 + kc);
        for (int mt = 0; mt < 4; ++mt)
            for (int nt = 0; nt < 4; ++nt)
                acc[mt][nt] = __builtin_amdgcn_mfma_f32_16x16x32_bf16(a[mt], bb[nt], acc[mt][nt], 0, 0, 0);
    }

    const int side = w >> 1;
    const int ebase = (w & 1) * 64;
#pragma unroll
    for (int ph = 0; ph < 2; ++ph) {
        __syncthreads();
#pragma unroll
        for (int mh = 0; mh < 2; ++mh) {
            int mt = ph * 2 + mh;
#pragma unroll
            for (int nt = 0; nt < 4; ++nt)
#pragma unroll
                for (int r = 0; r < 4; ++r) {
                    int q32 = mh * 16 + q4 * 4 + r;
                    Ost[side][q32][ebase + nt * 16 + l15] = f2bf(acc[mt][nt][r]);
                }
        }
        __syncthreads();
#pragma unroll
        for (int s = 0; s < 4; ++s) {
            int idx = tid + s * 256;
            int sd = idx >> 9, rem = idx & 511;
            int r32 = rem >> 4, c8 = rem & 15;
            unsigned short* dst = sd ? Kbf : Qbf;
            int c8s = sd ? (c8 ^ (r32 & 15)) : c8;   // pre-swizzle K only
            *(uint4*)(dst + ((size_t)b * NHW + qt + ph * 32 + r32) * NE + c8s * 8) =
                *(const uint4*)&Ost[sd][r32][c8 * 8];
        }
    }
}

// ---------------- K2: flash attention, producer/consumer wave specialization.
// Block 512 thr = 8 waves, q-tile 128, k-tile 64, 65 rounds, 1 LDS-only barrier/round.
// Waves 0-3 (SIMD 0-3) PRODUCE: round i: QK S^T[64k x 32q] (16 MFMA, A=K from
//   DMA'd LDS, B=Q regs) -> softmax -> in-reg P^T B-frags -> 4 conflict-free
//   ds_write_b128 into Pu[buf i&1].
// Waves 4-7 (SIMD 0-3) CONSUME: round i: PV O^T[64c x 128q] (32 MFMA, A=V
//   global-direct frags (R6-verified), B=P^T from Pu[buf (i-1)&1]).
// K feed: __builtin_amdgcn_global_load_lds dbuf; producers vmcnt(0) before the
// round barrier (full-round slack). Each SIMD: 1P+1C -> QK/softmax/PV always
// overlapped; matrix pipe demand 48 MFMA * 32cyc = 1536 cyc/round/SIMD.
// R5 (vs R0): P critical path shaved, register-neutral -- (1) lane^32 P^T
// exchange via 4x v_permlane32_swap_b32 (branchless; replaces 8 shfl_xor +
// divergent hi/lo construction; mapping lane-algebra-verified vs R0 exchange),
// (2) row-sum via depth-4 tree instead of 32-deep serial add chain.
// NOTE (R1/R3/R4 post-mortems): this kernel sits at exactly the 512-reg/SIMD
// file limit (128 VGPR + 128 AGPR x 2 waves/SIMD).  Do NOT add loop-carried
// state (spills: R3) or waves (halves budget: R1); homogeneous waves lose the
// P/C overlap (R4).
// LDS: Ku dbuf 32K | Pu dbuf 32K | lsum 512B.
__global__ __launch_bounds__(512, 2) void attn_kernel(const unsigned short* __restrict__ Qbf,
                                                      const unsigned short* __restrict__ Kbf,
                                                      const unsigned short* __restrict__ Vbf,
                                                      float* __restrict__ out) {
    __shared__ __align__(16) unsigned char smem[66048];
    unsigned short* KuS = (unsigned short*)smem;             // 2 x 16KB, swizzled tiles
    unsigned short* PuS = (unsigned short*)(smem + 32768);   // 2 x 16 frag-tiles x 1KB
    float* lsumF = (float*)(smem + 65536);                   // [4][32]

    const int tid = threadIdx.x;
    const int b = blockIdx.x & 7;                            // batch -> XCD affinity
    const int q128 = (blockIdx.x >> 3) << 7;
    const int w = tid >> 6;                                  // wave 0-7 -> SIMD w&3
    const int L = tid & 63;
    const int l31 = L & 31, hi = L >> 5;
    const int x15 = l31 & 15;

    const unsigned short* Kb = Kbf + (size_t)b * NHW * NE;
    const unsigned short* Vb = Vbf + (size_t)b * NC * NHW;

    v16f o[2][4];                                            // consumer acc [ct][qt], 128 AGPR
#pragma unroll
    for (int ct = 0; ct < 2; ++ct)
#pragma unroll
        for (int qt = 0; qt < 4; ++qt)
#pragma unroll
            for (int r = 0; r < 16; ++r) o[ct][qt][r] = 0.f;
    float lacc = 0.f;                                        // producer row-sum partial

    v8bf bq[8];                                              // producer Q B-frags
    v8bf av[2][4];                                           // consumer V A-frags
    const unsigned short* vb0 = nullptr;
    const unsigned short* vb1 = nullptr;

    if (w < 4) {
        // producer prologue: Q frags + DMA K tile 0 into buf 0
        const unsigned short* qrow = Qbf + ((size_t)b * NHW + q128 + w * 32 + l31) * NE + hi * 8;
#pragma unroll
        for (int ef = 0; ef < 8; ++ef)
            bq[ef] = *(const v8bf*)(qrow + ef * 16);
#pragma unroll
        for (int jj = 0; jj < 4; ++jj) {
            int j = w * 4 + jj;
            dma16(Kb + (size_t)j * 512 + L * 8, KuS + j * 512);
        }
        WAIT_VM0();
    } else {
        // consumer prologue: V frags tile 0
        int ci = w - 4;
        vb0 = Vb + (size_t)(ci * 64 + l31) * NHW + hi * 8;
        vb1 = Vb + (size_t)(ci * 64 + 32 + l31) * NHW + hi * 8;
#pragma unroll
        for (int kf = 0; kf < 4; ++kf) {
            av[0][kf] = *(const v8bf*)(vb0 + kf * 16);
            av[1][kf] = *(const v8bf*)(vb1 + kf * 16);
        }
    }
    BARRIER_LDS();

    for (int it = 0; it < 65; ++it) {
        if (w < 4 && it < 64) {
            // ================= PRODUCER round i =================
            const int buf = it & 1;
            const int nbuf = (it + 1) & 1;
            const size_t ktn = (size_t)((it + 1) & 63) * 64;
            // DMA next K tile (drained by vmcnt(0) at round end)
#pragma unroll
            for (int jj = 0; jj < 4; ++jj) {
                int j = w * 4 + jj;
                dma16(Kb + ktn * NE + (size_t)j * 512 + L * 8, KuS + nbuf * 8192 + j * 512);
            }
            const unsigned short* kub = KuS + buf * 8192;
#pragma unroll
            for (int kt = 0; kt < 2; ++kt) {
                // QK: S^T[32k x 32q], two 4-deep chains (A=K, B=Q) -- R5-verified reads
                v16f sa, sb;
#pragma unroll
                for (int r = 0; r < 16; ++r) { sa[r] = 0.f; sb[r] = 0.f; }
                const unsigned short* krow = kub + (kt * 32 + l31) * 128;
#pragma unroll
                for (int ef = 0; ef < 4; ++ef) {
                    v8bf ak0 = *(const v8bf*)(krow + (((2 * ef + hi) ^ x15) * 8));
                    v8bf ak1 = *(const v8bf*)(krow + (((2 * (ef + 4) + hi) ^ x15) * 8));
                    sa = __builtin_amdgcn_mfma_f32_32x32x16_bf16(ak0, bq[ef], sa, 0, 0, 0);
                    sb = __builtin_amdgcn_mfma_f32_32x32x16_bf16(ak1, bq[ef + 4], sb, 0, 0, 0);
                }
                // softmax (scale*log2e folded into Q); lane owns q-col l31
                float p[16];
#pragma unroll
                for (int r = 0; r < 16; ++r) p[r] = EXP2F(sa[r] + sb[r]);
                // row-sum: depth-4 tree (was 16-deep serial chain / kt)
                {
                    float t0 = (p[0] + p[1]) + (p[2] + p[3]);
                    float t1 = (p[4] + p[5]) + (p[6] + p[7]);
                    float t2 = (p[8] + p[9]) + (p[10] + p[11]);
                    float t3 = (p[12] + p[13]) + (p[14] + p[15]);
                    lacc += (t0 + t1) + (t2 + t3);
                }
                // P^T B-frags in regs: pack then branchless cross-half exchange.
                // PERMSWAP32(pk[2t], pk[2t+2]) yields f-words for BOTH lane halves:
                //   a'[l<32]=pk2t(l)      (hi=0 word0)   a'[l>=32]=pk2t+2(l-32) (hi=1 word0=px)
                //   b'[l<32]=pk2t(l+32)=px (hi=0 word2)  b'[l>=32]=pk2t+2(l)   (hi=1 word2)
                // == R0's {pk0,pk1,px0,px1}/{px2,px3,pk2,pk3} selection, no divergence.
                unsigned int pk[8];
#pragma unroll
                for (int t = 0; t < 8; ++t) pk[t] = pack_bf2_ru(p[2 * t], p[2 * t + 1]);
                unsigned int a0 = pk[0], b0 = pk[2];
                unsigned int a1 = pk[1], b1 = pk[3];
                unsigned int a2 = pk[4], b2 = pk[6];
                unsigned int a3 = pk[5], b3 = pk[7];
                PERMSWAP32(a0, b0);
                PERMSWAP32(a1, b1);
                PERMSWAP32(a2, b2);
                PERMSWAP32(a3, b3);
                union { v4u u; v8bf bb; } f0, f1;
                f0.u = (v4u){a0, a1, b0, b1};
                f1.u = (v4u){a2, a3, b2, b3};
                // share: frag-tile (qsub=w, kf=kt*2+{0,1}), unit = hi*32+l31 (lane-major,
                // conflict-free b128: consecutive lanes -> consecutive 16B)
                unsigned short* pw_ = PuS + buf * 8192 + (w * 4 + kt * 2) * 512 + (hi * 32 + l31) * 8;
                *(v4u*)pw_ = f0.u;
                *(v4u*)(pw_ + 512) = f1.u;
            }
            WAIT_VM0();                                      // DMA(i+1) landed before next round
        }
        if (w >= 4 && it > 0) {
            // ================= CONSUMER round i: PV over tile it-1 =================
            const int pbuf = (it - 1) & 1;
            const unsigned short* pb = PuS + pbuf * 8192 + (hi * 32 + l31) * 8;
#pragma unroll
            for (int qt = 0; qt < 4; ++qt) {
                v8bf bp[4];
#pragma unroll
                for (int kf = 0; kf < 4; ++kf)
                    bp[kf] = *(const v8bf*)(pb + (qt * 4 + kf) * 512);
#pragma unroll
                for (int kf = 0; kf < 4; ++kf) {
                    o[0][qt] = __builtin_amdgcn_mfma_f32_32x32x16_bf16(av[0][kf], bp[kf], o[0][qt], 0, 0, 0);
                    o[1][qt] = __builtin_amdgcn_mfma_f32_32x32x16_bf16(av[1][kf], bp[kf], o[1][qt], 0, 0, 0);
                }
            }
            // reload V frags for tile it (consumed next round; ~full round slack)
            const size_t kc0 = (size_t)(it & 63) * 64;
#pragma unroll
            for (int kf = 0; kf < 4; ++kf) {
                av[0][kf] = *(const v8bf*)(vb0 + kc0 + kf * 16);
                av[1][kf] = *(const v8bf*)(vb1 + kc0 + kf * 16);
            }
        }
        BARRIER_LDS();                                       // single round barrier
    }

    // ---- row-sum handoff: producers -> lsum -> consumers
    if (w < 4) {
        float tot = lacc + __shfl_xor(lacc, 32);
        if (hi == 0) lsumF[w * 32 + l31] = tot;
    }
    BARRIER_LDS();
    if (w >= 4) {
        const int ci = w - 4;
        float inv[4];
#pragma unroll
        for (int qt = 0; qt < 4; ++qt) inv[qt] = 1.0f / lsumF[qt * 32 + l31];
        // store: O^T C/D lane = q-col -> coalesced dwords
#pragma unroll
        for (int ct = 0; ct < 2; ++ct)
#pragma unroll
            for (int qt = 0; qt < 4; ++qt) {
                float* ob = out + (size_t)b * NC * NHW + q128 + qt * 32 + l31;
#pragma unroll
                for (int r = 0; r < 16; ++r) {
                    int c = ci * 64 + ct * 32 + (r & 3) + 8 * (r >> 2) + 4 * hi;
                    ob[(size_t)c * NHW] = o[ct][qt][r] * inv[qt];
                }
            }
    }
}

extern "C" void kernel_launch(void* const* d_in, const int* in_sizes, int n_in,
                              void* d_out, int out_size, void* d_ws, size_t ws_size,
                              hipStream_t stream) {
    const float* l  = (const float*)d_in[0];
    const float* wt = (const float*)d_in[1];
    const float* wp = (const float*)d_in[2];
    float* out = (float*)d_out;

    char* ws = (char*)d_ws;
    unsigned short* Wbf = (unsigned short*)ws;                          // 131072 B
    unsigned short* Qbf = (unsigned short*)(ws + 131072);               // 8 MB
    unsigned short* Kbf = (unsigned short*)(ws + 131072 + 8388608);     // 8 MB (pre-swizzled)
    unsigned short* Vbf = (unsigned short*)(ws + 131072 + 16777216);    // 16 MB

    hipLaunchKernelGGL(cast_w_kernel, dim3(256), dim3(256), 0, stream, wt, wp, Wbf);
    hipLaunchKernelGGL(proj_kernel,   dim3(512), dim3(256), 0, stream, l, Wbf, Qbf, Kbf, Vbf);
    hipLaunchKernelGGL(attn_kernel,   dim3(256), dim3(512), 0, stream, Qbf, Kbf, Vbf, out);
}

// Round 6
// 224.286 us; speedup vs baseline: 1.8783x; 1.5783x over previous
//
#include <hip/hip_runtime.h>
#include <stdint.h>

#define NB 8
#define NC 256
#define NE 128
#define NHW 4096

typedef __bf16 v8bf __attribute__((ext_vector_type(8)));
typedef float v4f __attribute__((ext_vector_type(4)));
typedef float v16f __attribute__((ext_vector_type(16)));
typedef unsigned int v4u __attribute__((ext_vector_type(4)));

typedef unsigned int __attribute__((address_space(1))) uint_g;
typedef unsigned int __attribute__((address_space(3))) uint_l;

#if __has_builtin(__builtin_amdgcn_exp2f)
#define EXP2F(x) __builtin_amdgcn_exp2f(x)
#else
#define EXP2F(x) exp2f(x)
#endif

// LDS-only barrier: drains lgkmcnt but NOT vmcnt (global prefetch/DMA stays in flight)
#define BARRIER_LDS() asm volatile("s_waitcnt lgkmcnt(0)\n\ts_barrier" ::: "memory")
#define WAIT_VM0()    asm volatile("s_waitcnt vmcnt(0)" ::: "memory")

// async global->LDS DMA, 16B per lane: LDS dst = uniform base + lane*16
__device__ __forceinline__ void dma16(const unsigned short* g, unsigned short* l) {
    __builtin_amdgcn_global_load_lds((const uint_g*)g, (uint_l*)l, 16, 0, 0);
}

// fp32 -> bf16 round-to-nearest-even
__device__ __forceinline__ unsigned short f2bf(float x) {
    union { float f; unsigned int u; } v; v.f = x;
    unsigned int r = v.u + 0x7fffu + ((v.u >> 16) & 1u);
    return (unsigned short)(r >> 16);
}

// pack two fp32 -> bf16x2, round-half-up (P in (0,1], R4-verified accuracy)
__device__ __forceinline__ unsigned int pack_bf2_ru(float a, float b) {
    union { float f; unsigned int u; } va, vb; va.f = a; vb.f = b;
    return ((va.u + 0x8000u) >> 16) | ((vb.u + 0x8000u) & 0xffff0000u);
}

// ---------------- K0: cast weights. Wbf[e][c], e<128 = w_theta*(scale*log2e), e>=128 = w_phi
__global__ __launch_bounds__(256) void cast_w_kernel(const float* __restrict__ wt,
                                                     const float* __restrict__ wp,
                                                     unsigned short* __restrict__ Wbf) {
    int i = blockIdx.x * 256 + threadIdx.x;
    const float QS = 0.08838834764831845f * 1.4426950408889634f;
    float v = (i < 32768) ? wt[i] * QS : wp[i - 32768];
    Wbf[i] = f2bf(v);
}

// ---------------- K1: projection (+ fused V cast). K is stored PRE-SWIZZLED
// (16B unit u at position u ^ (row&15) within each row) so attn's LDS DMA copy
// is read conflict-free with the R5-verified fragment pattern. Q unswizzled.
// R6: hw-tile 64 -> 32. Grid 512 -> 1024 (4 blocks/CU), LDS 51 -> 34.5 KB,
// stage loop 16 -> 8 iters, Ost epilogue 2 phases -> 1 (2 fewer barriers),
// acc[4][4] -> acc[2][4].  Same total l/V/Q/K bytes; W re-reads double but are
// L2-resident.  Phase latency now overlaps 4-way across blocks (was 2-way).
__global__ __launch_bounds__(256, 4) void proj_kernel(const float* __restrict__ l,
                                                      const unsigned short* __restrict__ Wbf,
                                                      unsigned short* __restrict__ Qbf,
                                                      unsigned short* __restrict__ Kbf,
                                                      unsigned short* __restrict__ Vbf) {
    __shared__ __align__(16) unsigned short A[32][264];
    __shared__ __align__(16) unsigned short Ost[2][32][136];
    const int tid = threadIdx.x;
    const int b = blockIdx.x & 7;
    const int qt = (blockIdx.x >> 3) << 5;
    const float* lb = l + ((size_t)b * NC * NHW + qt);

    for (int s = 0; s < 8; ++s) {
        int f = tid + s * 256;
        int c = f >> 3, j = f & 7;                 // c: channel 0..255, j: hw-quad 0..7
        float4 v = *(const float4*)(lb + (size_t)c * NHW + j * 4);
        ushort4 o4;
        o4.x = f2bf(v.x); o4.y = f2bf(v.y); o4.z = f2bf(v.z); o4.w = f2bf(v.w);
        A[j * 4 + 0][c] = o4.x;
        A[j * 4 + 1][c] = o4.y;
        A[j * 4 + 2][c] = o4.z;
        A[j * 4 + 3][c] = o4.w;
        *(ushort4*)(Vbf + (size_t)b * NC * NHW + (size_t)c * NHW + qt + j * 4) = o4;
    }
    __syncthreads();

    const int w = tid >> 6, L = tid & 63;
    const int l15 = L & 15, q4 = L >> 4;
    const v4f vz = {0.f, 0.f, 0.f, 0.f};
    v4f acc[2][4];
    for (int mt = 0; mt < 2; ++mt)
        for (int nt = 0; nt < 4; ++nt) acc[mt][nt] = vz;

    for (int kf = 0; kf < 8; ++kf) {
        int kc = kf * 32 + q4 * 8;
        v8bf a[2], bb[4];
        for (int mt = 0; mt < 2; ++mt)
            a[mt] = *(const v8bf*)&A[mt * 16 + l15][kc];
        for (int nt = 0; nt < 4; ++nt)
            bb[nt] = *(const v8bf*)(Wbf + (w * 64 + nt * 16 + l15) * 256 + kc);
        for (int mt = 0; mt < 2; ++mt)
            for (int nt = 0; nt < 4; ++nt)
                acc[mt][nt] = __builtin_amdgcn_mfma_f32_16x16x32_bf16(a[mt], bb[nt], acc[mt][nt], 0, 0, 0);
    }

    const int side = w >> 1;                        // w<2: theta->Q, w>=2: phi->K
    const int ebase = (w & 1) * 64;
    __syncthreads();
#pragma unroll
    for (int mt = 0; mt < 2; ++mt)
#pragma unroll
        for (int nt = 0; nt < 4; ++nt)
#pragma unroll
            for (int r = 0; r < 4; ++r) {
                int q32 = mt * 16 + q4 * 4 + r;
                Ost[side][q32][ebase + nt * 16 + l15] = f2bf(acc[mt][nt][r]);
            }
    __syncthreads();
#pragma unroll
    for (int s = 0; s < 4; ++s) {
        int idx = tid + s * 256;
        int sd = idx >> 9, rem = idx & 511;
        int r32 = rem >> 4, c8 = rem & 15;
        unsigned short* dst = sd ? Kbf : Qbf;
        int c8s = sd ? (c8 ^ (r32 & 15)) : c8;      // pre-swizzle K only
        *(uint4*)(dst + ((size_t)b * NHW + qt + r32) * NE + c8s * 8) =
            *(const uint4*)&Ost[sd][r32][c8 * 8];
    }
}

// ---------------- K2: flash attention, producer/consumer wave specialization.
// Block 512 thr = 8 waves, q-tile 128, k-tile 64, 65 rounds, 1 LDS-only barrier/round.
// Waves 0-3 (SIMD 0-3) PRODUCE: round i: QK S^T[64k x 32q] (16 MFMA, A=K from
//   DMA'd LDS, B=Q regs) -> softmax -> in-reg P^T B-frags (R3-verified lane^32
//   exchange) -> 4 conflict-free ds_write_b128 into Pu[buf i&1].
// Waves 4-7 (SIMD 0-3) CONSUME: round i: PV O^T[64c x 128q] (32 MFMA, A=V
//   global-direct frags (R6-verified), B=P^T from Pu[buf (i-1)&1]).
// K feed: __builtin_amdgcn_global_load_lds dbuf; producers vmcnt(0) before the
// round barrier (full-round slack). Each SIMD: 1P+1C -> QK/softmax/PV always
// overlapped; matrix pipe demand 48 MFMA * 32cyc = 1536 cyc/round/SIMD.
// LDS: Ku dbuf 32K | Pu dbuf 32K | lsum 512B.
// FROZEN at the R0-verified form (144.5 us).  R1/R3/R4/R5 post-mortems: this
// kernel sits at exactly the 512-reg/SIMD file limit (128 VGPR + 128 AGPR x
// 2 waves/SIMD).  Adding waves (R1), loop-carried pipeline state (R3), or
// substituting the exchange instructions (R5) all tip the allocator into
// scratch (WRITE_SIZE 39 -> 98-308 MB); homogeneous waves (R4) lose the P/C
// overlap.  Do not perturb without new register headroom.
__global__ __launch_bounds__(512, 2) void attn_kernel(const unsigned short* __restrict__ Qbf,
                                                      const unsigned short* __restrict__ Kbf,
                                                      const unsigned short* __restrict__ Vbf,
                                                      float* __restrict__ out) {
    __shared__ __align__(16) unsigned char smem[66048];
    unsigned short* KuS = (unsigned short*)smem;             // 2 x 16KB, swizzled tiles
    unsigned short* PuS = (unsigned short*)(smem + 32768);   // 2 x 16 frag-tiles x 1KB
    float* lsumF = (float*)(smem + 65536);                   // [4][32]

    const int tid = threadIdx.x;
    const int b = blockIdx.x & 7;                            // batch -> XCD affinity
    const int q128 = (blockIdx.x >> 3) << 7;
    const int w = tid >> 6;                                  // wave 0-7 -> SIMD w&3
    const int L = tid & 63;
    const int l31 = L & 31, hi = L >> 5;
    const int x15 = l31 & 15;

    const unsigned short* Kb = Kbf + (size_t)b * NHW * NE;
    const unsigned short* Vb = Vbf + (size_t)b * NC * NHW;

    v16f o[2][4];                                            // consumer acc [ct][qt], 128 AGPR
#pragma unroll
    for (int ct = 0; ct < 2; ++ct)
#pragma unroll
        for (int qt = 0; qt < 4; ++qt)
#pragma unroll
            for (int r = 0; r < 16; ++r) o[ct][qt][r] = 0.f;
    float lacc = 0.f;                                        // producer row-sum partial

    v8bf bq[8];                                              // producer Q B-frags
    v8bf av[2][4];                                           // consumer V A-frags
    const unsigned short* vb0 = nullptr;
    const unsigned short* vb1 = nullptr;

    if (w < 4) {
        // producer prologue: Q frags + DMA K tile 0 into buf 0
        const unsigned short* qrow = Qbf + ((size_t)b * NHW + q128 + w * 32 + l31) * NE + hi * 8;
#pragma unroll
        for (int ef = 0; ef < 8; ++ef)
            bq[ef] = *(const v8bf*)(qrow + ef * 16);
#pragma unroll
        for (int jj = 0; jj < 4; ++jj) {
            int j = w * 4 + jj;
            dma16(Kb + (size_t)j * 512 + L * 8, KuS + j * 512);
        }
        WAIT_VM0();
    } else {
        // consumer prologue: V frags tile 0
        int ci = w - 4;
        vb0 = Vb + (size_t)(ci * 64 + l31) * NHW + hi * 8;
        vb1 = Vb + (size_t)(ci * 64 + 32 + l31) * NHW + hi * 8;
#pragma unroll
        for (int kf = 0; kf < 4; ++kf) {
            av[0][kf] = *(const v8bf*)(vb0 + kf * 16);
            av[1][kf] = *(const v8bf*)(vb1 + kf * 16);
        }
    }
    BARRIER_LDS();

    for (int it = 0; it < 65; ++it) {
        if (w < 4 && it < 64) {
            // ================= PRODUCER round i =================
            const int buf = it & 1;
            const int nbuf = (it + 1) & 1;
            const size_t ktn = (size_t)((it + 1) & 63) * 64;
            // DMA next K tile (drained by vmcnt(0) at round end)
#pragma unroll
            for (int jj = 0; jj < 4; ++jj) {
                int j = w * 4 + jj;
                dma16(Kb + ktn * NE + (size_t)j * 512 + L * 8, KuS + nbuf * 8192 + j * 512);
            }
            const unsigned short* kub = KuS + buf * 8192;
#pragma unroll
            for (int kt = 0; kt < 2; ++kt) {
                // QK: S^T[32k x 32q], two 4-deep chains (A=K, B=Q) -- R5-verified reads
                v16f sa, sb;
#pragma unroll
                for (int r = 0; r < 16; ++r) { sa[r] = 0.f; sb[r] = 0.f; }
                const unsigned short* krow = kub + (kt * 32 + l31) * 128;
#pragma unroll
                for (int ef = 0; ef < 4; ++ef) {
                    v8bf ak0 = *(const v8bf*)(krow + (((2 * ef + hi) ^ x15) * 8));
                    v8bf ak1 = *(const v8bf*)(krow + (((2 * (ef + 4) + hi) ^ x15) * 8));
                    sa = __builtin_amdgcn_mfma_f32_32x32x16_bf16(ak0, bq[ef], sa, 0, 0, 0);
                    sb = __builtin_amdgcn_mfma_f32_32x32x16_bf16(ak1, bq[ef + 4], sb, 0, 0, 0);
                }
                // softmax (scale*log2e folded into Q); lane owns q-col l31
                float p[16];
#pragma unroll
                for (int r = 0; r < 16; ++r) p[r] = EXP2F(sa[r] + sb[r]);
#pragma unroll
                for (int r = 0; r < 16; ++r) lacc += p[r];
                // P^T B-frags in regs (R3/R8-verified exchange)
                unsigned int pk[8], px[8];
#pragma unroll
                for (int t = 0; t < 8; ++t) pk[t] = pack_bf2_ru(p[2 * t], p[2 * t + 1]);
#pragma unroll
                for (int t = 0; t < 8; ++t) px[t] = (unsigned int)__shfl_xor((int)pk[t], 32);
                union { v4u u; v8bf bb; } f0, f1;
                if (hi == 0) {
                    f0.u = (v4u){pk[0], pk[1], px[0], px[1]};
                    f1.u = (v4u){pk[4], pk[5], px[4], px[5]};
                } else {
                    f0.u = (v4u){px[2], px[3], pk[2], pk[3]};
                    f1.u = (v4u){px[6], px[7], pk[6], pk[7]};
                }
                // share: frag-tile (qsub=w, kf=kt*2+{0,1}), unit = hi*32+l31 (lane-major,
                // conflict-free b128: consecutive lanes -> consecutive 16B)
                unsigned short* pw_ = PuS + buf * 8192 + (w * 4 + kt * 2) * 512 + (hi * 32 + l31) * 8;
                *(v4u*)pw_ = f0.u;
                *(v4u*)(pw_ + 512) = f1.u;
            }
            WAIT_VM0();                                      // DMA(i+1) landed before next round
        }
        if (w >= 4 && it > 0) {
            // ================= CONSUMER round i: PV over tile it-1 =================
            const int pbuf = (it - 1) & 1;
            const unsigned short* pb = PuS + pbuf * 8192 + (hi * 32 + l31) * 8;
#pragma unroll
            for (int qt = 0; qt < 4; ++qt) {
                v8bf bp[4];
#pragma unroll
                for (int kf = 0; kf < 4; ++kf)
                    bp[kf] = *(const v8bf*)(pb + (qt * 4 + kf) * 512);
#pragma unroll
                for (int kf = 0; kf < 4; ++kf) {
                    o[0][qt] = __builtin_amdgcn_mfma_f32_32x32x16_bf16(av[0][kf], bp[kf], o[0][qt], 0, 0, 0);
                    o[1][qt] = __builtin_amdgcn_mfma_f32_32x32x16_bf16(av[1][kf], bp[kf], o[1][qt], 0, 0, 0);
                }
            }
            // reload V frags for tile it (consumed next round; ~full round slack)
            const size_t kc0 = (size_t)(it & 63) * 64;
#pragma unroll
            for (int kf = 0; kf < 4; ++kf) {
                av[0][kf] = *(const v8bf*)(vb0 + kc0 + kf * 16);
                av[1][kf] = *(const v8bf*)(vb1 + kc0 + kf * 16);
            }
        }
        BARRIER_LDS();                                       // single round barrier
    }

    // ---- row-sum handoff: producers -> lsum -> consumers
    if (w < 4) {
        float tot = lacc + __shfl_xor(lacc, 32);
        if (hi == 0) lsumF[w * 32 + l31] = tot;
    }
    BARRIER_LDS();
    if (w >= 4) {
        const int ci = w - 4;
        float inv[4];
#pragma unroll
        for (int qt = 0; qt < 4; ++qt) inv[qt] = 1.0f / lsumF[qt * 32 + l31];
        // store: O^T C/D lane = q-col -> coalesced dwords
#pragma unroll
        for (int ct = 0; ct < 2; ++ct)
#pragma unroll
            for (int qt = 0; qt < 4; ++qt) {
                float* ob = out + (size_t)b * NC * NHW + q128 + qt * 32 + l31;
#pragma unroll
                for (int r = 0; r < 16; ++r) {
                    int c = ci * 64 + ct * 32 + (r & 3) + 8 * (r >> 2) + 4 * hi;
                    ob[(size_t)c * NHW] = o[ct][qt][r] * inv[qt];
                }
            }
    }
}

extern "C" void kernel_launch(void* const* d_in, const int* in_sizes, int n_in,
                              void* d_out, int out_size, void* d_ws, size_t ws_size,
                              hipStream_t stream) {
    const float* l  = (const float*)d_in[0];
    const float* wt = (const float*)d_in[1];
    const float* wp = (const float*)d_in[2];
    float* out = (float*)d_out;

    char* ws = (char*)d_ws;
    unsigned short* Wbf = (unsigned short*)ws;                          // 131072 B
    unsigned short* Qbf = (unsigned short*)(ws + 131072);               // 8 MB
    unsigned short* Kbf = (unsigned short*)(ws + 131072 + 8388608);     // 8 MB (pre-swizzled)
    unsigned short* Vbf = (unsigned short*)(ws + 131072 + 16777216);    // 16 MB

    hipLaunchKernelGGL(cast_w_kernel, dim3(256),  dim3(256), 0, stream, wt, wp, Wbf);
    hipLaunchKernelGGL(proj_kernel,   dim3(1024), dim3(256), 0, stream, l, Wbf, Qbf, Kbf, Vbf);
    hipLaunchKernelGGL(attn_kernel,   dim3(256),  dim3(512), 0, stream, Qbf, Kbf, Vbf, out);
}

// Round 7
// 221.539 us; speedup vs baseline: 1.9016x; 1.0124x over previous
//
#include <hip/hip_runtime.h>
#include <stdint.h>

#define NB 8
#define NC 256
#define NE 128
#define NHW 4096

typedef __bf16 v8bf __attribute__((ext_vector_type(8)));
typedef float v4f __attribute__((ext_vector_type(4)));
typedef float v16f __attribute__((ext_vector_type(16)));
typedef unsigned int v4u __attribute__((ext_vector_type(4)));

typedef unsigned int __attribute__((address_space(1))) uint_g;
typedef unsigned int __attribute__((address_space(3))) uint_l;

#if __has_builtin(__builtin_amdgcn_exp2f)
#define EXP2F(x) __builtin_amdgcn_exp2f(x)
#else
#define EXP2F(x) exp2f(x)
#endif

// LDS-only barrier: drains lgkmcnt but NOT vmcnt (global prefetch/DMA stays in flight)
#define BARRIER_LDS() asm volatile("s_waitcnt lgkmcnt(0)\n\ts_barrier" ::: "memory")
#define WAIT_VM0()    asm volatile("s_waitcnt vmcnt(0)" ::: "memory")

// async global->LDS DMA, 16B per lane: LDS dst = uniform base + lane*16
__device__ __forceinline__ void dma16(const unsigned short* g, unsigned short* l) {
    __builtin_amdgcn_global_load_lds((const uint_g*)g, (uint_l*)l, 16, 0, 0);
}

// fp32 -> bf16 round-to-nearest-even
__device__ __forceinline__ unsigned short f2bf(float x) {
    union { float f; unsigned int u; } v; v.f = x;
    unsigned int r = v.u + 0x7fffu + ((v.u >> 16) & 1u);
    return (unsigned short)(r >> 16);
}

// pack two fp32 -> bf16x2, round-half-up (P in (0,1], R4-verified accuracy)
__device__ __forceinline__ unsigned int pack_bf2_ru(float a, float b) {
    union { float f; unsigned int u; } va, vb; va.f = a; vb.f = b;
    return ((va.u + 0x8000u) >> 16) | ((vb.u + 0x8000u) & 0xffff0000u);
}

// ---------------- K0: cast weights. Wbf[e][c], e<128 = w_theta*(scale*log2e), e>=128 = w_phi
__global__ __launch_bounds__(256) void cast_w_kernel(const float* __restrict__ wt,
                                                     const float* __restrict__ wp,
                                                     unsigned short* __restrict__ Wbf) {
    int i = blockIdx.x * 256 + threadIdx.x;
    const float QS = 0.08838834764831845f * 1.4426950408889634f;
    float v = (i < 32768) ? wt[i] * QS : wp[i - 32768];
    Wbf[i] = f2bf(v);
}

// ---------------- K1: projection (+ fused V cast). K is stored PRE-SWIZZLED
// (16B unit u at position u ^ (row&15) within each row) so attn's LDS DMA copy
// is read conflict-free with the R5-verified fragment pattern. Q unswizzled.
// R7: reverted to the R0-exact 64-hw-tile form.  R6's 32-tile variant
// regressed +13 us: per-block W reads (131 KB, full Wbf) doubled to 134 MB of
// L2 traffic and per-channel read segments halved (256B->128B); 4-way phase
// overlap did not compensate.  W amortization wants BIGGER tiles, not smaller.
__global__ __launch_bounds__(256, 2) void proj_kernel(const float* __restrict__ l,
                                                      const unsigned short* __restrict__ Wbf,
                                                      unsigned short* __restrict__ Qbf,
                                                      unsigned short* __restrict__ Kbf,
                                                      unsigned short* __restrict__ Vbf) {
    __shared__ __align__(16) unsigned short A[64][264];
    __shared__ __align__(16) unsigned short Ost[2][32][136];
    const int tid = threadIdx.x;
    const int b = blockIdx.x & 7;
    const int qt = (blockIdx.x >> 3) << 6;
    const float* lb = l + ((size_t)b * NC * NHW + qt);

    for (int s = 0; s < 16; ++s) {
        int f = tid + s * 256;
        int c = f >> 4, j = f & 15;
        float4 v = *(const float4*)(lb + (size_t)c * NHW + j * 4);
        ushort4 o4;
        o4.x = f2bf(v.x); o4.y = f2bf(v.y); o4.z = f2bf(v.z); o4.w = f2bf(v.w);
        A[j * 4 + 0][c] = o4.x;
        A[j * 4 + 1][c] = o4.y;
        A[j * 4 + 2][c] = o4.z;
        A[j * 4 + 3][c] = o4.w;
        *(ushort4*)(Vbf + (size_t)b * NC * NHW + (size_t)c * NHW + qt + j * 4) = o4;
    }
    __syncthreads();

    const int w = tid >> 6, L = tid & 63;
    const int l15 = L & 15, q4 = L >> 4;
    const v4f vz = {0.f, 0.f, 0.f, 0.f};
    v4f acc[4][4];
    for (int mt = 0; mt < 4; ++mt)
        for (int nt = 0; nt < 4; ++nt) acc[mt][nt] = vz;

    for (int kf = 0; kf < 8; ++kf) {
        int kc = kf * 32 + q4 * 8;
        v8bf a[4], bb[4];
        for (int mt = 0; mt < 4; ++mt)
            a[mt] = *(const v8bf*)&A[mt * 16 + l15][kc];
        for (int nt = 0; nt < 4; ++nt)
            bb[nt] = *(const v8bf*)(Wbf + (w * 64 + nt * 16 + l15) * 256 + kc);
        for (int mt = 0; mt < 4; ++mt)
            for (int nt = 0; nt < 4; ++nt)
                acc[mt][nt] = __builtin_amdgcn_mfma_f32_16x16x32_bf16(a[mt], bb[nt], acc[mt][nt], 0, 0, 0);
    }

    const int side = w >> 1;
    const int ebase = (w & 1) * 64;
#pragma unroll
    for (int ph = 0; ph < 2; ++ph) {
        __syncthreads();
#pragma unroll
        for (int mh = 0; mh < 2; ++mh) {
            int mt = ph * 2 + mh;
#pragma unroll
            for (int nt = 0; nt < 4; ++nt)
#pragma unroll
                for (int r = 0; r < 4; ++r) {
                    int q32 = mh * 16 + q4 * 4 + r;
                    Ost[side][q32][ebase + nt * 16 + l15] = f2bf(acc[mt][nt][r]);
                }
        }
        __syncthreads();
#pragma unroll
        for (int s = 0; s < 4; ++s) {
            int idx = tid + s * 256;
            int sd = idx >> 9, rem = idx & 511;
            int r32 = rem >> 4, c8 = rem & 15;
            unsigned short* dst = sd ? Kbf : Qbf;
            int c8s = sd ? (c8 ^ (r32 & 15)) : c8;   // pre-swizzle K only
            *(uint4*)(dst + ((size_t)b * NHW + qt + ph * 32 + r32) * NE + c8s * 8) =
                *(const uint4*)&Ost[sd][r32][c8 * 8];
        }
    }
}

// ---------------- K2: flash attention, producer/consumer wave specialization.
// Block 512 thr = 8 waves, q-tile 128, k-tile 64, 65 rounds, 1 LDS-only barrier/round.
// Waves 0-3 (SIMD 0-3) PRODUCE: round i: QK S^T[64k x 32q] (16 MFMA, A=K from
//   DMA'd LDS, B=Q regs) -> softmax -> in-reg P^T B-frags (R3-verified lane^32
//   exchange) -> 4 conflict-free ds_write_b128 into Pu[buf i&1].
// Waves 4-7 (SIMD 0-3) CONSUME: round i: PV O^T[64c x 128q] (32 MFMA, A=V
//   global-direct frags (R6-verified), B=P^T from Pu[buf (i-1)&1]).
// K feed: __builtin_amdgcn_global_load_lds dbuf; producers vmcnt(0) before the
// round barrier (full-round slack). Each SIMD: 1P+1C -> QK/softmax/PV always
// overlapped; matrix pipe demand 48 MFMA * 32cyc = 1536 cyc/round/SIMD.
// R7 (vs R0): ONLY change is s_setprio(1)/(0) around both MFMA clusters (T5:
// each SIMD hosts 1P+1C at different phases -> scheduler has roles to
// arbitrate; zero register cost, the only lever that cannot spill).
// FROZEN otherwise.  R1/R3/R4/R5 post-mortems: this kernel sits at exactly the
// 512-reg/SIMD file limit (128 VGPR + 128 AGPR x 2 waves/SIMD).  Adding waves
// (R1), loop-carried pipeline state (R3), or substituting the exchange
// instructions (R5) all tip the allocator into scratch (WRITE_SIZE 39 ->
// 98-308 MB); homogeneous waves (R4) lose the P/C overlap.
// LDS: Ku dbuf 32K | Pu dbuf 32K | lsum 512B.
__global__ __launch_bounds__(512, 2) void attn_kernel(const unsigned short* __restrict__ Qbf,
                                                      const unsigned short* __restrict__ Kbf,
                                                      const unsigned short* __restrict__ Vbf,
                                                      float* __restrict__ out) {
    __shared__ __align__(16) unsigned char smem[66048];
    unsigned short* KuS = (unsigned short*)smem;             // 2 x 16KB, swizzled tiles
    unsigned short* PuS = (unsigned short*)(smem + 32768);   // 2 x 16 frag-tiles x 1KB
    float* lsumF = (float*)(smem + 65536);                   // [4][32]

    const int tid = threadIdx.x;
    const int b = blockIdx.x & 7;                            // batch -> XCD affinity
    const int q128 = (blockIdx.x >> 3) << 7;
    const int w = tid >> 6;                                  // wave 0-7 -> SIMD w&3
    const int L = tid & 63;
    const int l31 = L & 31, hi = L >> 5;
    const int x15 = l31 & 15;

    const unsigned short* Kb = Kbf + (size_t)b * NHW * NE;
    const unsigned short* Vb = Vbf + (size_t)b * NC * NHW;

    v16f o[2][4];                                            // consumer acc [ct][qt], 128 AGPR
#pragma unroll
    for (int ct = 0; ct < 2; ++ct)
#pragma unroll
        for (int qt = 0; qt < 4; ++qt)
#pragma unroll
            for (int r = 0; r < 16; ++r) o[ct][qt][r] = 0.f;
    float lacc = 0.f;                                        // producer row-sum partial

    v8bf bq[8];                                              // producer Q B-frags
    v8bf av[2][4];                                           // consumer V A-frags
    const unsigned short* vb0 = nullptr;
    const unsigned short* vb1 = nullptr;

    if (w < 4) {
        // producer prologue: Q frags + DMA K tile 0 into buf 0
        const unsigned short* qrow = Qbf + ((size_t)b * NHW + q128 + w * 32 + l31) * NE + hi * 8;
#pragma unroll
        for (int ef = 0; ef < 8; ++ef)
            bq[ef] = *(const v8bf*)(qrow + ef * 16);
#pragma unroll
        for (int jj = 0; jj < 4; ++jj) {
            int j = w * 4 + jj;
            dma16(Kb + (size_t)j * 512 + L * 8, KuS + j * 512);
        }
        WAIT_VM0();
    } else {
        // consumer prologue: V frags tile 0
        int ci = w - 4;
        vb0 = Vb + (size_t)(ci * 64 + l31) * NHW + hi * 8;
        vb1 = Vb + (size_t)(ci * 64 + 32 + l31) * NHW + hi * 8;
#pragma unroll
        for (int kf = 0; kf < 4; ++kf) {
            av[0][kf] = *(const v8bf*)(vb0 + kf * 16);
            av[1][kf] = *(const v8bf*)(vb1 + kf * 16);
        }
    }
    BARRIER_LDS();

    for (int it = 0; it < 65; ++it) {
        if (w < 4 && it < 64) {
            // ================= PRODUCER round i =================
            const int buf = it & 1;
            const int nbuf = (it + 1) & 1;
            const size_t ktn = (size_t)((it + 1) & 63) * 64;
            // DMA next K tile (drained by vmcnt(0) at round end)
#pragma unroll
            for (int jj = 0; jj < 4; ++jj) {
                int j = w * 4 + jj;
                dma16(Kb + ktn * NE + (size_t)j * 512 + L * 8, KuS + nbuf * 8192 + j * 512);
            }
            const unsigned short* kub = KuS + buf * 8192;
#pragma unroll
            for (int kt = 0; kt < 2; ++kt) {
                // QK: S^T[32k x 32q], two 4-deep chains (A=K, B=Q) -- R5-verified reads
                v16f sa, sb;
#pragma unroll
                for (int r = 0; r < 16; ++r) { sa[r] = 0.f; sb[r] = 0.f; }
                const unsigned short* krow = kub + (kt * 32 + l31) * 128;
                __builtin_amdgcn_s_setprio(1);
#pragma unroll
                for (int ef = 0; ef < 4; ++ef) {
                    v8bf ak0 = *(const v8bf*)(krow + (((2 * ef + hi) ^ x15) * 8));
                    v8bf ak1 = *(const v8bf*)(krow + (((2 * (ef + 4) + hi) ^ x15) * 8));
                    sa = __builtin_amdgcn_mfma_f32_32x32x16_bf16(ak0, bq[ef], sa, 0, 0, 0);
                    sb = __builtin_amdgcn_mfma_f32_32x32x16_bf16(ak1, bq[ef + 4], sb, 0, 0, 0);
                }
                __builtin_amdgcn_s_setprio(0);
                // softmax (scale*log2e folded into Q); lane owns q-col l31
                float p[16];
#pragma unroll
                for (int r = 0; r < 16; ++r) p[r] = EXP2F(sa[r] + sb[r]);
#pragma unroll
                for (int r = 0; r < 16; ++r) lacc += p[r];
                // P^T B-frags in regs (R3/R8-verified exchange)
                unsigned int pk[8], px[8];
#pragma unroll
                for (int t = 0; t < 8; ++t) pk[t] = pack_bf2_ru(p[2 * t], p[2 * t + 1]);
#pragma unroll
                for (int t = 0; t < 8; ++t) px[t] = (unsigned int)__shfl_xor((int)pk[t], 32);
                union { v4u u; v8bf bb; } f0, f1;
                if (hi == 0) {
                    f0.u = (v4u){pk[0], pk[1], px[0], px[1]};
                    f1.u = (v4u){pk[4], pk[5], px[4], px[5]};
                } else {
                    f0.u = (v4u){px[2], px[3], pk[2], pk[3]};
                    f1.u = (v4u){px[6], px[7], pk[6], pk[7]};
                }
                // share: frag-tile (qsub=w, kf=kt*2+{0,1}), unit = hi*32+l31 (lane-major,
                // conflict-free b128: consecutive lanes -> consecutive 16B)
                unsigned short* pw_ = PuS + buf * 8192 + (w * 4 + kt * 2) * 512 + (hi * 32 + l31) * 8;
                *(v4u*)pw_ = f0.u;
                *(v4u*)(pw_ + 512) = f1.u;
            }
            WAIT_VM0();                                      // DMA(i+1) landed before next round
        }
        if (w >= 4 && it > 0) {
            // ================= CONSUMER round i: PV over tile it-1 =================
            const int pbuf = (it - 1) & 1;
            const unsigned short* pb = PuS + pbuf * 8192 + (hi * 32 + l31) * 8;
            __builtin_amdgcn_s_setprio(1);
#pragma unroll
            for (int qt = 0; qt < 4; ++qt) {
                v8bf bp[4];
#pragma unroll
                for (int kf = 0; kf < 4; ++kf)
                    bp[kf] = *(const v8bf*)(pb + (qt * 4 + kf) * 512);
#pragma unroll
                for (int kf = 0; kf < 4; ++kf) {
                    o[0][qt] = __builtin_amdgcn_mfma_f32_32x32x16_bf16(av[0][kf], bp[kf], o[0][qt], 0, 0, 0);
                    o[1][qt] = __builtin_amdgcn_mfma_f32_32x32x16_bf16(av[1][kf], bp[kf], o[1][qt], 0, 0, 0);
                }
            }
            __builtin_amdgcn_s_setprio(0);
            // reload V frags for tile it (consumed next round; ~full round slack)
            const size_t kc0 = (size_t)(it & 63) * 64;
#pragma unroll
            for (int kf = 0; kf < 4; ++kf) {
                av[0][kf] = *(const v8bf*)(vb0 + kc0 + kf * 16);
                av[1][kf] = *(const v8bf*)(vb1 + kc0 + kf * 16);
            }
        }
        BARRIER_LDS();                                       // single round barrier
    }

    // ---- row-sum handoff: producers -> lsum -> consumers
    if (w < 4) {
        float tot = lacc + __shfl_xor(lacc, 32);
        if (hi == 0) lsumF[w * 32 + l31] = tot;
    }
    BARRIER_LDS();
    if (w >= 4) {
        const int ci = w - 4;
        float inv[4];
#pragma unroll
        for (int qt = 0; qt < 4; ++qt) inv[qt] = 1.0f / lsumF[qt * 32 + l31];
        // store: O^T C/D lane = q-col -> coalesced dwords
#pragma unroll
        for (int ct = 0; ct < 2; ++ct)
#pragma unroll
            for (int qt = 0; qt < 4; ++qt) {
                float* ob = out + (size_t)b * NC * NHW + q128 + qt * 32 + l31;
#pragma unroll
                for (int r = 0; r < 16; ++r) {
                    int c = ci * 64 + ct * 32 + (r & 3) + 8 * (r >> 2) + 4 * hi;
                    ob[(size_t)c * NHW] = o[ct][qt][r] * inv[qt];
                }
            }
    }
}

extern "C" void kernel_launch(void* const* d_in, const int* in_sizes, int n_in,
                              void* d_out, int out_size, void* d_ws, size_t ws_size,
                              hipStream_t stream) {
    const float* l  = (const float*)d_in[0];
    const float* wt = (const float*)d_in[1];
    const float* wp = (const float*)d_in[2];
    float* out = (float*)d_out;

    char* ws = (char*)d_ws;
    unsigned short* Wbf = (unsigned short*)ws;                          // 131072 B
    unsigned short* Qbf = (unsigned short*)(ws + 131072);               // 8 MB
    unsigned short* Kbf = (unsigned short*)(ws + 131072 + 8388608);     // 8 MB (pre-swizzled)
    unsigned short* Vbf = (unsigned short*)(ws + 131072 + 16777216);    // 16 MB

    hipLaunchKernelGGL(cast_w_kernel, dim3(256), dim3(256), 0, stream, wt, wp, Wbf);
    hipLaunchKernelGGL(proj_kernel,   dim3(512), dim3(256), 0, stream, l, Wbf, Qbf, Kbf, Vbf);
    hipLaunchKernelGGL(attn_kernel,   dim3(256), dim3(512), 0, stream, Qbf, Kbf, Vbf, out);
}

// Round 8
// 205.820 us; speedup vs baseline: 2.0469x; 1.0764x over previous
//
#include <hip/hip_runtime.h>
#include <stdint.h>

#define NB 8
#define NC 256
#define NE 128
#define NHW 4096

typedef __bf16 v8bf __attribute__((ext_vector_type(8)));
typedef float v4f __attribute__((ext_vector_type(4)));
typedef float v16f __attribute__((ext_vector_type(16)));
typedef unsigned int v4u __attribute__((ext_vector_type(4)));

typedef unsigned int __attribute__((address_space(1))) uint_g;
typedef unsigned int __attribute__((address_space(3))) uint_l;

#if __has_builtin(__builtin_amdgcn_exp2f)
#define EXP2F(x) __builtin_amdgcn_exp2f(x)
#else
#define EXP2F(x) exp2f(x)
#endif

// LDS-only barrier: drains lgkmcnt but NOT vmcnt (global prefetch/DMA stays in flight)
#define BARRIER_LDS() asm volatile("s_waitcnt lgkmcnt(0)\n\ts_barrier" ::: "memory")
#define WAIT_VM0()    asm volatile("s_waitcnt vmcnt(0)" ::: "memory")

// async global->LDS DMA, 16B per lane: LDS dst = uniform base + lane*16
__device__ __forceinline__ void dma16(const unsigned short* g, unsigned short* l) {
    __builtin_amdgcn_global_load_lds((const uint_g*)g, (uint_l*)l, 16, 0, 0);
}

// fp32 -> bf16 round-to-nearest-even
__device__ __forceinline__ unsigned short f2bf(float x) {
    union { float f; unsigned int u; } v; v.f = x;
    unsigned int r = v.u + 0x7fffu + ((v.u >> 16) & 1u);
    return (unsigned short)(r >> 16);
}

// pack two fp32 -> bf16x2, round-half-up (P in (0,1], R4-verified accuracy)
__device__ __forceinline__ unsigned int pack_bf2_ru(float a, float b) {
    union { float f; unsigned int u; } va, vb; va.f = a; vb.f = b;
    return ((va.u + 0x8000u) >> 16) | ((vb.u + 0x8000u) & 0xffff0000u);
}

// ---------------- K0: cast weights. Wbf[e][c], e<128 = w_theta*(scale*log2e), e>=128 = w_phi
__global__ __launch_bounds__(256) void cast_w_kernel(const float* __restrict__ wt,
                                                     const float* __restrict__ wp,
                                                     unsigned short* __restrict__ Wbf) {
    int i = blockIdx.x * 256 + threadIdx.x;
    const float QS = 0.08838834764831845f * 1.4426950408889634f;
    float v = (i < 32768) ? wt[i] * QS : wp[i - 32768];
    Wbf[i] = f2bf(v);
}

// ---------------- K1: projection (+ fused V cast). K is stored PRE-SWIZZLED
// (16B unit u at position u ^ (row&15) within each row) so attn's LDS DMA copy
// is read conflict-free with the R5-verified fragment pattern. Q unswizzled.
// R0-exact form (R6's 32-tile variant regressed: W re-read doubling).
__global__ __launch_bounds__(256, 2) void proj_kernel(const float* __restrict__ l,
                                                      const unsigned short* __restrict__ Wbf,
                                                      unsigned short* __restrict__ Qbf,
                                                      unsigned short* __restrict__ Kbf,
                                                      unsigned short* __restrict__ Vbf) {
    __shared__ __align__(16) unsigned short A[64][264];
    __shared__ __align__(16) unsigned short Ost[2][32][136];
    const int tid = threadIdx.x;
    const int b = blockIdx.x & 7;
    const int qt = (blockIdx.x >> 3) << 6;
    const float* lb = l + ((size_t)b * NC * NHW + qt);

    for (int s = 0; s < 16; ++s) {
        int f = tid + s * 256;
        int c = f >> 4, j = f & 15;
        float4 v = *(const float4*)(lb + (size_t)c * NHW + j * 4);
        ushort4 o4;
        o4.x = f2bf(v.x); o4.y = f2bf(v.y); o4.z = f2bf(v.z); o4.w = f2bf(v.w);
        A[j * 4 + 0][c] = o4.x;
        A[j * 4 + 1][c] = o4.y;
        A[j * 4 + 2][c] = o4.z;
        A[j * 4 + 3][c] = o4.w;
        *(ushort4*)(Vbf + (size_t)b * NC * NHW + (size_t)c * NHW + qt + j * 4) = o4;
    }
    __syncthreads();

    const int w = tid >> 6, L = tid & 63;
    const int l15 = L & 15, q4 = L >> 4;
    const v4f vz = {0.f, 0.f, 0.f, 0.f};
    v4f acc[4][4];
    for (int mt = 0; mt < 4; ++mt)
        for (int nt = 0; nt < 4; ++nt) acc[mt][nt] = vz;

    for (int kf = 0; kf < 8; ++kf) {
        int kc = kf * 32 + q4 * 8;
        v8bf a[4], bb[4];
        for (int mt = 0; mt < 4; ++mt)
            a[mt] = *(const v8bf*)&A[mt * 16 + l15][kc];
        for (int nt = 0; nt < 4; ++nt)
            bb[nt] = *(const v8bf*)(Wbf + (w * 64 + nt * 16 + l15) * 256 + kc);
        for (int mt = 0; mt < 4; ++mt)
            for (int nt = 0; nt < 4; ++nt)
                acc[mt][nt] = __builtin_amdgcn_mfma_f32_16x16x32_bf16(a[mt], bb[nt], acc[mt][nt], 0, 0, 0);
    }

    const int side = w >> 1;
    const int ebase = (w & 1) * 64;
#pragma unroll
    for (int ph = 0; ph < 2; ++ph) {
        __syncthreads();
#pragma unroll
        for (int mh = 0; mh < 2; ++mh) {
            int mt = ph * 2 + mh;
#pragma unroll
            for (int nt = 0; nt < 4; ++nt)
#pragma unroll
                for (int r = 0; r < 4; ++r) {
                    int q32 = mh * 16 + q4 * 4 + r;
                    Ost[side][q32][ebase + nt * 16 + l15] = f2bf(acc[mt][nt][r]);
                }
        }
        __syncthreads();
#pragma unroll
        for (int s = 0; s < 4; ++s) {
            int idx = tid + s * 256;
            int sd = idx >> 9, rem = idx & 511;
            int r32 = rem >> 4, c8 = rem & 15;
            unsigned short* dst = sd ? Kbf : Qbf;
            int c8s = sd ? (c8 ^ (r32 & 15)) : c8;   // pre-swizzle K only
            *(uint4*)(dst + ((size_t)b * NHW + qt + ph * 32 + r32) * NE + c8s * 8) =
                *(const uint4*)&Ost[sd][r32][c8 * 8];
        }
    }
}

// ---------------- K2: flash attention, SPLIT-LOOP producer/consumer wave
// specialization (R8).  R1-R5 post-mortem: in the single-loop form, the
// consumer acc o[2][4] (128 regs) is live-through the producer's code region,
// leaving P only ~128 regs -> every pipelining attempt spilled.  Here P and C
// have DISJOINT code regions, each with its own 65-iteration loop; the raw
// s_barrier count is identical on both sides (1 prologue + 1 prologue-B/idle +
// 65 loop + 1 epilogue = 68), so the workgroup stays barrier-synchronized
// round-for-round exactly like R0.  Liveness decoupled -> P regains ~110 regs
// of headroom, spent on the R2 software pipeline: iter i runs DMA K(i+2) ||
// QK(i+1) (independent MFMA) || softmax(i) from register-resident s_prev.
// Buffer parities identical to the audited R2 schedule: P writes Pu[i&1], C
// reads Pu[(i-1)&1]; QK reads Ku[(i+1)&1], DMA fills Ku[i&1].  Math and
// accumulation order bit-identical to R0.  No setprio (R7 A/B: -8%).
// Waves 0-3 PRODUCE: QK S^T[64k x 32q] (16 MFMA, A=K from DMA'd LDS, B=Q regs)
//   -> softmax(prev) -> in-reg P^T B-frags (lane^32 exchange) -> 4 ds_write_b128.
// Waves 4-7 CONSUME: PV O^T[64c x 128q] (32 MFMA, A=V global-direct frags,
//   B=P^T from Pu).
// LDS: Ku dbuf 32K | Pu dbuf 32K | lsum 512B.
__global__ __launch_bounds__(512, 2) void attn_kernel(const unsigned short* __restrict__ Qbf,
                                                      const unsigned short* __restrict__ Kbf,
                                                      const unsigned short* __restrict__ Vbf,
                                                      float* __restrict__ out) {
    __shared__ __align__(16) unsigned char smem[66048];
    unsigned short* KuS = (unsigned short*)smem;             // 2 x 16KB, swizzled tiles
    unsigned short* PuS = (unsigned short*)(smem + 32768);   // 2 x 16 frag-tiles x 1KB
    float* lsumF = (float*)(smem + 65536);                   // [4][32]

    const int tid = threadIdx.x;
    const int b = blockIdx.x & 7;                            // batch -> XCD affinity
    const int q128 = (blockIdx.x >> 3) << 7;
    const int w = tid >> 6;                                  // wave 0-7 -> SIMD w&3
    const int L = tid & 63;
    const int l31 = L & 31, hi = L >> 5;
    const int x15 = l31 & 15;

    const unsigned short* Kb = Kbf + (size_t)b * NHW * NE;
    const unsigned short* Vb = Vbf + (size_t)b * NC * NHW;

    if (w < 4) {
        // ==================== PRODUCER region ====================
        float lacc = 0.f;
        v8bf bq[8];
        const unsigned short* qrow = Qbf + ((size_t)b * NHW + q128 + w * 32 + l31) * NE + hi * 8;
#pragma unroll
        for (int ef = 0; ef < 8; ++ef)
            bq[ef] = *(const v8bf*)(qrow + ef * 16);
        // prologue A: DMA K tile 0 -> buf 0
#pragma unroll
        for (int jj = 0; jj < 4; ++jj) {
            int j = w * 4 + jj;
            dma16(Kb + (size_t)j * 512 + L * 8, KuS + j * 512);
        }
        WAIT_VM0();
        BARRIER_LDS();                                       // barrier #1
        // prologue B: DMA K(1) -> buf 1; QK(0) -> s_prev
#pragma unroll
        for (int jj = 0; jj < 4; ++jj) {
            int j = w * 4 + jj;
            dma16(Kb + (size_t)64 * NE + (size_t)j * 512 + L * 8, KuS + 8192 + j * 512);
        }
        v16f s_prev[2];
        {
            const unsigned short* kub = KuS;
#pragma unroll
            for (int kt = 0; kt < 2; ++kt) {
                v16f sa, sb;
#pragma unroll
                for (int r = 0; r < 16; ++r) { sa[r] = 0.f; sb[r] = 0.f; }
                const unsigned short* krow = kub + (kt * 32 + l31) * 128;
#pragma unroll
                for (int ef = 0; ef < 4; ++ef) {
                    v8bf ak0 = *(const v8bf*)(krow + (((2 * ef + hi) ^ x15) * 8));
                    v8bf ak1 = *(const v8bf*)(krow + (((2 * (ef + 4) + hi) ^ x15) * 8));
                    sa = __builtin_amdgcn_mfma_f32_32x32x16_bf16(ak0, bq[ef], sa, 0, 0, 0);
                    sb = __builtin_amdgcn_mfma_f32_32x32x16_bf16(ak1, bq[ef + 4], sb, 0, 0, 0);
                }
#pragma unroll
                for (int r = 0; r < 16; ++r) s_prev[kt][r] = sa[r] + sb[r];
            }
        }
        WAIT_VM0();                                          // DMA(1) landed
        BARRIER_LDS();                                       // barrier #2

        for (int it = 0; it < 65; ++it) {
            if (it < 64) {
                const int buf = it & 1;                      // Pu publish buf; DMA(i+2) Ku buf
                if (it <= 61) {
                    // DMA K(i+2) into Ku buf[(i+2)&1] = buf[i&1] (tile i dead: QK'd last iter)
                    const size_t ktn = (size_t)(it + 2) * 64;
#pragma unroll
                    for (int jj = 0; jj < 4; ++jj) {
                        int j = w * 4 + jj;
                        dma16(Kb + ktn * NE + (size_t)j * 512 + L * 8, KuS + buf * 8192 + j * 512);
                    }
                }
                v16f s_new[2];
                if (it <= 62) {
                    // QK(i+1): reads Ku buf[(i+1)&1], landed + barrier'd last iter
                    const unsigned short* kub = KuS + ((it + 1) & 1) * 8192;
#pragma unroll
                    for (int kt = 0; kt < 2; ++kt) {
                        v16f sa, sb;
#pragma unroll
                        for (int r = 0; r < 16; ++r) { sa[r] = 0.f; sb[r] = 0.f; }
                        const unsigned short* krow = kub + (kt * 32 + l31) * 128;
#pragma unroll
                        for (int ef = 0; ef < 4; ++ef) {
                            v8bf ak0 = *(const v8bf*)(krow + (((2 * ef + hi) ^ x15) * 8));
                            v8bf ak1 = *(const v8bf*)(krow + (((2 * (ef + 4) + hi) ^ x15) * 8));
                            sa = __builtin_amdgcn_mfma_f32_32x32x16_bf16(ak0, bq[ef], sa, 0, 0, 0);
                            sb = __builtin_amdgcn_mfma_f32_32x32x16_bf16(ak1, bq[ef + 4], sb, 0, 0, 0);
                        }
#pragma unroll
                        for (int r = 0; r < 16; ++r) s_new[kt][r] = sa[r] + sb[r];
                    }
                }
                // softmax(i) from s_prev -- independent of this iter's MFMAs
#pragma unroll
                for (int kt = 0; kt < 2; ++kt) {
                    float p[16];
#pragma unroll
                    for (int r = 0; r < 16; ++r) p[r] = EXP2F(s_prev[kt][r]);
#pragma unroll
                    for (int r = 0; r < 16; ++r) lacc += p[r];
                    unsigned int pk[8], px[8];
#pragma unroll
                    for (int t = 0; t < 8; ++t) pk[t] = pack_bf2_ru(p[2 * t], p[2 * t + 1]);
#pragma unroll
                    for (int t = 0; t < 8; ++t) px[t] = (unsigned int)__shfl_xor((int)pk[t], 32);
                    union { v4u u; v8bf bb; } f0, f1;
                    if (hi == 0) {
                        f0.u = (v4u){pk[0], pk[1], px[0], px[1]};
                        f1.u = (v4u){pk[4], pk[5], px[4], px[5]};
                    } else {
                        f0.u = (v4u){px[2], px[3], pk[2], pk[3]};
                        f1.u = (v4u){px[6], px[7], pk[6], pk[7]};
                    }
                    unsigned short* pw_ = PuS + buf * 8192 + (w * 4 + kt * 2) * 512 + (hi * 32 + l31) * 8;
                    *(v4u*)pw_ = f0.u;
                    *(v4u*)(pw_ + 512) = f1.u;
                }
                if (it <= 62) {
                    s_prev[0] = s_new[0];
                    s_prev[1] = s_new[1];
                }
                WAIT_VM0();                                  // DMA(i+2) landed before barrier
            }
            BARRIER_LDS();                                   // barriers #3..#67
        }
        // epilogue: row-sum handoff
        float tot = lacc + __shfl_xor(lacc, 32);
        if (hi == 0) lsumF[w * 32 + l31] = tot;
        BARRIER_LDS();                                       // barrier #68
    } else {
        // ==================== CONSUMER region ====================
        const int ci = w - 4;
        v16f o[2][4];                                        // acc [ct][qt], 128 regs
#pragma unroll
        for (int ct = 0; ct < 2; ++ct)
#pragma unroll
            for (int qt = 0; qt < 4; ++qt)
#pragma unroll
                for (int r = 0; r < 16; ++r) o[ct][qt][r] = 0.f;
        const unsigned short* vb0 = Vb + (size_t)(ci * 64 + l31) * NHW + hi * 8;
        const unsigned short* vb1 = Vb + (size_t)(ci * 64 + 32 + l31) * NHW + hi * 8;
        v8bf av[2][4];
#pragma unroll
        for (int kf = 0; kf < 4; ++kf) {
            av[0][kf] = *(const v8bf*)(vb0 + kf * 16);
            av[1][kf] = *(const v8bf*)(vb1 + kf * 16);
        }
        BARRIER_LDS();                                       // barrier #1
        BARRIER_LDS();                                       // barrier #2 (P prologue B window)

        for (int it = 0; it < 65; ++it) {
            if (it > 0) {
                // PV over tile it-1 from Pu[(it-1)&1]
                const int pbuf = (it - 1) & 1;
                const unsigned short* pb = PuS + pbuf * 8192 + (hi * 32 + l31) * 8;
#pragma unroll
                for (int qt = 0; qt < 4; ++qt) {
                    v8bf bp[4];
#pragma unroll
                    for (int kf = 0; kf < 4; ++kf)
                        bp[kf] = *(const v8bf*)(pb + (qt * 4 + kf) * 512);
#pragma unroll
                    for (int kf = 0; kf < 4; ++kf) {
                        o[0][qt] = __builtin_amdgcn_mfma_f32_32x32x16_bf16(av[0][kf], bp[kf], o[0][qt], 0, 0, 0);
                        o[1][qt] = __builtin_amdgcn_mfma_f32_32x32x16_bf16(av[1][kf], bp[kf], o[1][qt], 0, 0, 0);
                    }
                }
                // reload V frags for tile it (consumed next iter; ~full round slack)
                const size_t kc0 = (size_t)(it & 63) * 64;
#pragma unroll
                for (int kf = 0; kf < 4; ++kf) {
                    av[0][kf] = *(const v8bf*)(vb0 + kc0 + kf * 16);
                    av[1][kf] = *(const v8bf*)(vb1 + kc0 + kf * 16);
                }
            }
            BARRIER_LDS();                                   // barriers #3..#67
        }
        BARRIER_LDS();                                       // barrier #68 (lsum ready)
        float inv[4];
#pragma unroll
        for (int qt = 0; qt < 4; ++qt) inv[qt] = 1.0f / lsumF[qt * 32 + l31];
        // store: O^T C/D lane = q-col -> coalesced dwords
#pragma unroll
        for (int ct = 0; ct < 2; ++ct)
#pragma unroll
            for (int qt = 0; qt < 4; ++qt) {
                float* ob = out + (size_t)b * NC * NHW + q128 + qt * 32 + l31;
#pragma unroll
                for (int r = 0; r < 16; ++r) {
                    int c = ci * 64 + ct * 32 + (r & 3) + 8 * (r >> 2) + 4 * hi;
                    ob[(size_t)c * NHW] = o[ct][qt][r] * inv[qt];
                }
            }
    }
}

extern "C" void kernel_launch(void* const* d_in, const int* in_sizes, int n_in,
                              void* d_out, int out_size, void* d_ws, size_t ws_size,
                              hipStream_t stream) {
    const float* l  = (const float*)d_in[0];
    const float* wt = (const float*)d_in[1];
    const float* wp = (const float*)d_in[2];
    float* out = (float*)d_out;

    char* ws = (char*)d_ws;
    unsigned short* Wbf = (unsigned short*)ws;                          // 131072 B
    unsigned short* Qbf = (unsigned short*)(ws + 131072);               // 8 MB
    unsigned short* Kbf = (unsigned short*)(ws + 131072 + 8388608);     // 8 MB (pre-swizzled)
    unsigned short* Vbf = (unsigned short*)(ws + 131072 + 16777216);    // 16 MB

    hipLaunchKernelGGL(cast_w_kernel, dim3(256), dim3(256), 0, stream, wt, wp, Wbf);
    hipLaunchKernelGGL(proj_kernel,   dim3(512), dim3(256), 0, stream, l, Wbf, Qbf, Kbf, Vbf);
    hipLaunchKernelGGL(attn_kernel,   dim3(256), dim3(512), 0, stream, Qbf, Kbf, Vbf, out);
}

// Round 9
// 199.475 us; speedup vs baseline: 2.1119x; 1.0318x over previous
//
#include <hip/hip_runtime.h>
#include <stdint.h>

#define NB 8
#define NC 256
#define NE 128
#define NHW 4096

typedef __bf16 v8bf __attribute__((ext_vector_type(8)));
typedef float v4f __attribute__((ext_vector_type(4)));
typedef float v16f __attribute__((ext_vector_type(16)));
typedef unsigned int v4u __attribute__((ext_vector_type(4)));
typedef unsigned int v2u __attribute__((ext_vector_type(2)));

typedef unsigned int __attribute__((address_space(1))) uint_g;
typedef unsigned int __attribute__((address_space(3))) uint_l;

#if __has_builtin(__builtin_amdgcn_exp2f)
#define EXP2F(x) __builtin_amdgcn_exp2f(x)
#else
#define EXP2F(x) exp2f(x)
#endif

// LDS-only barrier: drains lgkmcnt but NOT vmcnt (global prefetch/DMA stays in flight)
#define BARRIER_LDS() asm volatile("s_waitcnt lgkmcnt(0)\n\ts_barrier" ::: "memory")
#define WAIT_VM0()    asm volatile("s_waitcnt vmcnt(0)" ::: "memory")

// async global->LDS DMA, 16B per lane: LDS dst = uniform base + lane*16
__device__ __forceinline__ void dma16(const unsigned short* g, unsigned short* l) {
    __builtin_amdgcn_global_load_lds((const uint_g*)g, (uint_l*)l, 16, 0, 0);
}

// fp32 -> bf16 round-to-nearest-even
__device__ __forceinline__ unsigned short f2bf(float x) {
    union { float f; unsigned int u; } v; v.f = x;
    unsigned int r = v.u + 0x7fffu + ((v.u >> 16) & 1u);
    return (unsigned short)(r >> 16);
}

// pack two fp32 -> bf16x2, round-half-up (P in (0,1], R4-verified accuracy)
__device__ __forceinline__ unsigned int pack_bf2_ru(float a, float b) {
    union { float f; unsigned int u; } va, vb; va.f = a; vb.f = b;
    return ((va.u + 0x8000u) >> 16) | ((vb.u + 0x8000u) & 0xffff0000u);
}

// ---------------- K0: cast weights. Wbf[e][c], e<128 = w_theta*(scale*log2e), e>=128 = w_phi
__global__ __launch_bounds__(256) void cast_w_kernel(const float* __restrict__ wt,
                                                     const float* __restrict__ wp,
                                                     unsigned short* __restrict__ Wbf) {
    int i = blockIdx.x * 256 + threadIdx.x;
    const float QS = 0.08838834764831845f * 1.4426950408889634f;
    float v = (i < 32768) ? wt[i] * QS : wp[i - 32768];
    Wbf[i] = f2bf(v);
}

// ---------------- K1: projection (+ fused V cast). K is stored PRE-SWIZZLED
// (16B unit u at position u ^ (row&15) within each row) so attn's LDS DMA copy
// is read conflict-free with the R5-verified fragment pattern. Q unswizzled.
// R0-exact form (R6's 32-tile variant regressed: W re-read doubling).
__global__ __launch_bounds__(256, 2) void proj_kernel(const float* __restrict__ l,
                                                      const unsigned short* __restrict__ Wbf,
                                                      unsigned short* __restrict__ Qbf,
                                                      unsigned short* __restrict__ Kbf,
                                                      unsigned short* __restrict__ Vbf) {
    __shared__ __align__(16) unsigned short A[64][264];
    __shared__ __align__(16) unsigned short Ost[2][32][136];
    const int tid = threadIdx.x;
    const int b = blockIdx.x & 7;
    const int qt = (blockIdx.x >> 3) << 6;
    const float* lb = l + ((size_t)b * NC * NHW + qt);

    for (int s = 0; s < 16; ++s) {
        int f = tid + s * 256;
        int c = f >> 4, j = f & 15;
        float4 v = *(const float4*)(lb + (size_t)c * NHW + j * 4);
        ushort4 o4;
        o4.x = f2bf(v.x); o4.y = f2bf(v.y); o4.z = f2bf(v.z); o4.w = f2bf(v.w);
        A[j * 4 + 0][c] = o4.x;
        A[j * 4 + 1][c] = o4.y;
        A[j * 4 + 2][c] = o4.z;
        A[j * 4 + 3][c] = o4.w;
        *(ushort4*)(Vbf + (size_t)b * NC * NHW + (size_t)c * NHW + qt + j * 4) = o4;
    }
    __syncthreads();

    const int w = tid >> 6, L = tid & 63;
    const int l15 = L & 15, q4 = L >> 4;
    const v4f vz = {0.f, 0.f, 0.f, 0.f};
    v4f acc[4][4];
    for (int mt = 0; mt < 4; ++mt)
        for (int nt = 0; nt < 4; ++nt) acc[mt][nt] = vz;

    for (int kf = 0; kf < 8; ++kf) {
        int kc = kf * 32 + q4 * 8;
        v8bf a[4], bb[4];
        for (int mt = 0; mt < 4; ++mt)
            a[mt] = *(const v8bf*)&A[mt * 16 + l15][kc];
        for (int nt = 0; nt < 4; ++nt)
            bb[nt] = *(const v8bf*)(Wbf + (w * 64 + nt * 16 + l15) * 256 + kc);
        for (int mt = 0; mt < 4; ++mt)
            for (int nt = 0; nt < 4; ++nt)
                acc[mt][nt] = __builtin_amdgcn_mfma_f32_16x16x32_bf16(a[mt], bb[nt], acc[mt][nt], 0, 0, 0);
    }

    const int side = w >> 1;
    const int ebase = (w & 1) * 64;
#pragma unroll
    for (int ph = 0; ph < 2; ++ph) {
        __syncthreads();
#pragma unroll
        for (int mh = 0; mh < 2; ++mh) {
            int mt = ph * 2 + mh;
#pragma unroll
            for (int nt = 0; nt < 4; ++nt)
#pragma unroll
                for (int r = 0; r < 4; ++r) {
                    int q32 = mh * 16 + q4 * 4 + r;
                    Ost[side][q32][ebase + nt * 16 + l15] = f2bf(acc[mt][nt][r]);
                }
        }
        __syncthreads();
#pragma unroll
        for (int s = 0; s < 4; ++s) {
            int idx = tid + s * 256;
            int sd = idx >> 9, rem = idx & 511;
            int r32 = rem >> 4, c8 = rem & 15;
            unsigned short* dst = sd ? Kbf : Qbf;
            int c8s = sd ? (c8 ^ (r32 & 15)) : c8;   // pre-swizzle K only
            *(uint4*)(dst + ((size_t)b * NHW + qt + ph * 32 + r32) * NE + c8s * 8) =
                *(const uint4*)&Ost[sd][r32][c8 * 8];
        }
    }
}

// ---------------- K2: flash attention, SPLIT-LOOP producer/consumer wave
// specialization (R8 structure, verified: VGPR 96, zero spill, attn 130 us).
// P and C have DISJOINT code regions (liveness decoupled; R1-R5 lesson), each
// with its own 65-iter loop; raw s_barrier count identical on both sides
// (1 + 1 + 65 + 1 = 68) so the workgroup stays round-synchronized like R0.
// P runs the R2 software pipeline: iter i = DMA K(i+2) || QK(i+1) (independent
// MFMA) || softmax(i) from register-resident s_prev.
// R9 (vs R8): P-tail shave.  (1) The lane^32 P^T exchange (16 shfl_xor + 16
// selects + 4 ds_write_b128) is replaced by DIRECT SCATTER: each lane writes
// its packed words to the addresses the exchange would have produced --
// 8 ds_write_b64/round at addr1 = l31*16+hi*8 (+512B, +1KB tiles), memory
// image bit-identical (lane algebra: unit u<32 = [pk0(u),pk1(u),pk0(u+32),
// pk1(u+32)], u>=32 = [pk2(u-32),pk3(u-32),pk2(u),pk3(u)]).  b64 @ stride 16B
// = 4 words/bank = wave64 inherent minimum -> conflict-free.  (2) lacc via
// depth-4 tree (shorter dependent chain; more accurate, R5-verified passing).
// No setprio (R7 A/B: -8%).
// LDS: Ku dbuf 32K | Pu dbuf 32K | lsum 512B.
__global__ __launch_bounds__(512, 2) void attn_kernel(const unsigned short* __restrict__ Qbf,
                                                      const unsigned short* __restrict__ Kbf,
                                                      const unsigned short* __restrict__ Vbf,
                                                      float* __restrict__ out) {
    __shared__ __align__(16) unsigned char smem[66048];
    unsigned short* KuS = (unsigned short*)smem;             // 2 x 16KB, swizzled tiles
    unsigned short* PuS = (unsigned short*)(smem + 32768);   // 2 x 16 frag-tiles x 1KB
    float* lsumF = (float*)(smem + 65536);                   // [4][32]

    const int tid = threadIdx.x;
    const int b = blockIdx.x & 7;                            // batch -> XCD affinity
    const int q128 = (blockIdx.x >> 3) << 7;
    const int w = tid >> 6;                                  // wave 0-7 -> SIMD w&3
    const int L = tid & 63;
    const int l31 = L & 31, hi = L >> 5;
    const int x15 = l31 & 15;

    const unsigned short* Kb = Kbf + (size_t)b * NHW * NE;
    const unsigned short* Vb = Vbf + (size_t)b * NC * NHW;

    if (w < 4) {
        // ==================== PRODUCER region ====================
        float lacc = 0.f;
        v8bf bq[8];
        const unsigned short* qrow = Qbf + ((size_t)b * NHW + q128 + w * 32 + l31) * NE + hi * 8;
#pragma unroll
        for (int ef = 0; ef < 8; ++ef)
            bq[ef] = *(const v8bf*)(qrow + ef * 16);
        // prologue A: DMA K tile 0 -> buf 0
#pragma unroll
        for (int jj = 0; jj < 4; ++jj) {
            int j = w * 4 + jj;
            dma16(Kb + (size_t)j * 512 + L * 8, KuS + j * 512);
        }
        WAIT_VM0();
        BARRIER_LDS();                                       // barrier #1
        // prologue B: DMA K(1) -> buf 1; QK(0) -> s_prev
#pragma unroll
        for (int jj = 0; jj < 4; ++jj) {
            int j = w * 4 + jj;
            dma16(Kb + (size_t)64 * NE + (size_t)j * 512 + L * 8, KuS + 8192 + j * 512);
        }
        v16f s_prev[2];
        {
            const unsigned short* kub = KuS;
#pragma unroll
            for (int kt = 0; kt < 2; ++kt) {
                v16f sa, sb;
#pragma unroll
                for (int r = 0; r < 16; ++r) { sa[r] = 0.f; sb[r] = 0.f; }
                const unsigned short* krow = kub + (kt * 32 + l31) * 128;
#pragma unroll
                for (int ef = 0; ef < 4; ++ef) {
                    v8bf ak0 = *(const v8bf*)(krow + (((2 * ef + hi) ^ x15) * 8));
                    v8bf ak1 = *(const v8bf*)(krow + (((2 * (ef + 4) + hi) ^ x15) * 8));
                    sa = __builtin_amdgcn_mfma_f32_32x32x16_bf16(ak0, bq[ef], sa, 0, 0, 0);
                    sb = __builtin_amdgcn_mfma_f32_32x32x16_bf16(ak1, bq[ef + 4], sb, 0, 0, 0);
                }
#pragma unroll
                for (int r = 0; r < 16; ++r) s_prev[kt][r] = sa[r] + sb[r];
            }
        }
        WAIT_VM0();                                          // DMA(1) landed
        BARRIER_LDS();                                       // barrier #2

        // scatter-write address components (loop-invariant)
        const int a1 = l31 * 8 + hi * 4;                     // shorts: unit l31, word-half hi
        const int a2 = (l31 + 32) * 8 + hi * 4;              // shorts: unit l31+32, word-half hi

        for (int it = 0; it < 65; ++it) {
            if (it < 64) {
                const int buf = it & 1;                      // Pu publish buf; DMA(i+2) Ku buf
                if (it <= 61) {
                    // DMA K(i+2) into Ku buf[(i+2)&1] = buf[i&1] (tile i dead: QK'd last iter)
                    const size_t ktn = (size_t)(it + 2) * 64;
#pragma unroll
                    for (int jj = 0; jj < 4; ++jj) {
                        int j = w * 4 + jj;
                        dma16(Kb + ktn * NE + (size_t)j * 512 + L * 8, KuS + buf * 8192 + j * 512);
                    }
                }
                v16f s_new[2];
                if (it <= 62) {
                    // QK(i+1): reads Ku buf[(i+1)&1], landed + barrier'd last iter
                    const unsigned short* kub = KuS + ((it + 1) & 1) * 8192;
#pragma unroll
                    for (int kt = 0; kt < 2; ++kt) {
                        v16f sa, sb;
#pragma unroll
                        for (int r = 0; r < 16; ++r) { sa[r] = 0.f; sb[r] = 0.f; }
                        const unsigned short* krow = kub + (kt * 32 + l31) * 128;
#pragma unroll
                        for (int ef = 0; ef < 4; ++ef) {
                            v8bf ak0 = *(const v8bf*)(krow + (((2 * ef + hi) ^ x15) * 8));
                            v8bf ak1 = *(const v8bf*)(krow + (((2 * (ef + 4) + hi) ^ x15) * 8));
                            sa = __builtin_amdgcn_mfma_f32_32x32x16_bf16(ak0, bq[ef], sa, 0, 0, 0);
                            sb = __builtin_amdgcn_mfma_f32_32x32x16_bf16(ak1, bq[ef + 4], sb, 0, 0, 0);
                        }
#pragma unroll
                        for (int r = 0; r < 16; ++r) s_new[kt][r] = sa[r] + sb[r];
                    }
                }
                // softmax(i) from s_prev -- independent of this iter's MFMAs
#pragma unroll
                for (int kt = 0; kt < 2; ++kt) {
                    float p[16];
#pragma unroll
                    for (int r = 0; r < 16; ++r) p[r] = EXP2F(s_prev[kt][r]);
                    // row-sum: depth-4 tree (shorter dependent chain than 16 serial adds)
                    {
                        float t0 = (p[0] + p[1]) + (p[2] + p[3]);
                        float t1 = (p[4] + p[5]) + (p[6] + p[7]);
                        float t2 = (p[8] + p[9]) + (p[10] + p[11]);
                        float t3 = (p[12] + p[13]) + (p[14] + p[15]);
                        lacc += (t0 + t1) + (t2 + t3);
                    }
                    unsigned int pk[8];
#pragma unroll
                    for (int t = 0; t < 8; ++t) pk[t] = pack_bf2_ru(p[2 * t], p[2 * t + 1]);
                    // direct scatter: memory image identical to the R0-verified
                    // lane^32-exchange frags, without any cross-lane ops.
                    unsigned short* base0 = PuS + buf * 8192 + (w * 4 + kt * 2) * 512;
                    *(v2u*)(base0 + a1)       = (v2u){pk[0], pk[1]};
                    *(v2u*)(base0 + a2)       = (v2u){pk[2], pk[3]};
                    *(v2u*)(base0 + 512 + a1) = (v2u){pk[4], pk[5]};
                    *(v2u*)(base0 + 512 + a2) = (v2u){pk[6], pk[7]};
                }
                if (it <= 62) {
                    s_prev[0] = s_new[0];
                    s_prev[1] = s_new[1];
                }
                WAIT_VM0();                                  // DMA(i+2) landed before barrier
            }
            BARRIER_LDS();                                   // barriers #3..#67
        }
        // epilogue: row-sum handoff
        float tot = lacc + __shfl_xor(lacc, 32);
        if (hi == 0) lsumF[w * 32 + l31] = tot;
        BARRIER_LDS();                                       // barrier #68
    } else {
        // ==================== CONSUMER region ====================
        const int ci = w - 4;
        v16f o[2][4];                                        // acc [ct][qt], 128 regs
#pragma unroll
        for (int ct = 0; ct < 2; ++ct)
#pragma unroll
            for (int qt = 0; qt < 4; ++qt)
#pragma unroll
                for (int r = 0; r < 16; ++r) o[ct][qt][r] = 0.f;
        const unsigned short* vb0 = Vb + (size_t)(ci * 64 + l31) * NHW + hi * 8;
        const unsigned short* vb1 = Vb + (size_t)(ci * 64 + 32 + l31) * NHW + hi * 8;
        v8bf av[2][4];
#pragma unroll
        for (int kf = 0; kf < 4; ++kf) {
            av[0][kf] = *(const v8bf*)(vb0 + kf * 16);
            av[1][kf] = *(const v8bf*)(vb1 + kf * 16);
        }
        BARRIER_LDS();                                       // barrier #1
        BARRIER_LDS();                                       // barrier #2 (P prologue B window)

        for (int it = 0; it < 65; ++it) {
            if (it > 0) {
                // PV over tile it-1 from Pu[(it-1)&1]
                const int pbuf = (it - 1) & 1;
                const unsigned short* pb = PuS + pbuf * 8192 + (hi * 32 + l31) * 8;
#pragma unroll
                for (int qt = 0; qt < 4; ++qt) {
                    v8bf bp[4];
#pragma unroll
                    for (int kf = 0; kf < 4; ++kf)
                        bp[kf] = *(const v8bf*)(pb + (qt * 4 + kf) * 512);
#pragma unroll
                    for (int kf = 0; kf < 4; ++kf) {
                        o[0][qt] = __builtin_amdgcn_mfma_f32_32x32x16_bf16(av[0][kf], bp[kf], o[0][qt], 0, 0, 0);
                        o[1][qt] = __builtin_amdgcn_mfma_f32_32x32x16_bf16(av[1][kf], bp[kf], o[1][qt], 0, 0, 0);
                    }
                }
                // reload V frags for tile it (consumed next iter; ~full round slack)
                const size_t kc0 = (size_t)(it & 63) * 64;
#pragma unroll
                for (int kf = 0; kf < 4; ++kf) {
                    av[0][kf] = *(const v8bf*)(vb0 + kc0 + kf * 16);
                    av[1][kf] = *(const v8bf*)(vb1 + kc0 + kf * 16);
                }
            }
            BARRIER_LDS();                                   // barriers #3..#67
        }
        BARRIER_LDS();                                       // barrier #68 (lsum ready)
        float inv[4];
#pragma unroll
        for (int qt = 0; qt < 4; ++qt) inv[qt] = 1.0f / lsumF[qt * 32 + l31];
        // store: O^T C/D lane = q-col -> coalesced dwords
#pragma unroll
        for (int ct = 0; ct < 2; ++ct)
#pragma unroll
            for (int qt = 0; qt < 4; ++qt) {
                float* ob = out + (size_t)b * NC * NHW + q128 + qt * 32 + l31;
#pragma unroll
                for (int r = 0; r < 16; ++r) {
                    int c = ci * 64 + ct * 32 + (r & 3) + 8 * (r >> 2) + 4 * hi;
                    ob[(size_t)c * NHW] = o[ct][qt][r] * inv[qt];
                }
            }
    }
}

extern "C" void kernel_launch(void* const* d_in, const int* in_sizes, int n_in,
                              void* d_out, int out_size, void* d_ws, size_t ws_size,
                              hipStream_t stream) {
    const float* l  = (const float*)d_in[0];
    const float* wt = (const float*)d_in[1];
    const float* wp = (const float*)d_in[2];
    float* out = (float*)d_out;

    char* ws = (char*)d_ws;
    unsigned short* Wbf = (unsigned short*)ws;                          // 131072 B
    unsigned short* Qbf = (unsigned short*)(ws + 131072);               // 8 MB
    unsigned short* Kbf = (unsigned short*)(ws + 131072 + 8388608);     // 8 MB (pre-swizzled)
    unsigned short* Vbf = (unsigned short*)(ws + 131072 + 16777216);    // 16 MB

    hipLaunchKernelGGL(cast_w_kernel, dim3(256), dim3(256), 0, stream, wt, wp, Wbf);
    hipLaunchKernelGGL(proj_kernel,   dim3(512), dim3(256), 0, stream, l, Wbf, Qbf, Kbf, Vbf);
    hipLaunchKernelGGL(attn_kernel,   dim3(256), dim3(512), 0, stream, Qbf, Kbf, Vbf, out);
}

// Round 10
// 197.869 us; speedup vs baseline: 2.1291x; 1.0081x over previous
//
#include <hip/hip_runtime.h>
#include <stdint.h>

#define NB 8
#define NC 256
#define NE 128
#define NHW 4096

typedef __bf16 v8bf __attribute__((ext_vector_type(8)));
typedef float v4f __attribute__((ext_vector_type(4)));
typedef float v16f __attribute__((ext_vector_type(16)));
typedef unsigned int v4u __attribute__((ext_vector_type(4)));
typedef unsigned int v2u __attribute__((ext_vector_type(2)));

typedef unsigned int __attribute__((address_space(1))) uint_g;
typedef unsigned int __attribute__((address_space(3))) uint_l;

#if __has_builtin(__builtin_amdgcn_exp2f)
#define EXP2F(x) __builtin_amdgcn_exp2f(x)
#else
#define EXP2F(x) exp2f(x)
#endif

// LDS-only barrier: drains lgkmcnt but NOT vmcnt (global prefetch/DMA stays in flight)
#define BARRIER_LDS() asm volatile("s_waitcnt lgkmcnt(0)\n\ts_barrier" ::: "memory")
#define WAIT_VM0()    asm volatile("s_waitcnt vmcnt(0)" ::: "memory")

// async global->LDS DMA, 16B per lane: LDS dst = uniform base + lane*16
__device__ __forceinline__ void dma16(const unsigned short* g, unsigned short* l) {
    __builtin_amdgcn_global_load_lds((const uint_g*)g, (uint_l*)l, 16, 0, 0);
}

// fp32 -> bf16 round-to-nearest-even
__device__ __forceinline__ unsigned short f2bf(float x) {
    union { float f; unsigned int u; } v; v.f = x;
    unsigned int r = v.u + 0x7fffu + ((v.u >> 16) & 1u);
    return (unsigned short)(r >> 16);
}

// pack two fp32 -> bf16x2, round-half-up (P in (0,1], R4-verified accuracy)
__device__ __forceinline__ unsigned int pack_bf2_ru(float a, float b) {
    union { float f; unsigned int u; } va, vb; va.f = a; vb.f = b;
    return ((va.u + 0x8000u) >> 16) | ((vb.u + 0x8000u) & 0xffff0000u);
}

// ---------------- K0: cast weights. Wbf[e][c], e<128 = w_theta*(scale*log2e), e>=128 = w_phi
__global__ __launch_bounds__(256) void cast_w_kernel(const float* __restrict__ wt,
                                                     const float* __restrict__ wp,
                                                     unsigned short* __restrict__ Wbf) {
    int i = blockIdx.x * 256 + threadIdx.x;
    const float QS = 0.08838834764831845f * 1.4426950408889634f;
    float v = (i < 32768) ? wt[i] * QS : wp[i - 32768];
    Wbf[i] = f2bf(v);
}

// ---------------- K1: projection (+ fused V cast). K is stored PRE-SWIZZLED
// (16B unit u at position u ^ (row&15) within each row) so attn's LDS DMA copy
// is read conflict-free with the R5-verified fragment pattern. Q unswizzled.
// R0-exact form (R6's 32-tile variant regressed: W re-read doubling).
__global__ __launch_bounds__(256, 2) void proj_kernel(const float* __restrict__ l,
                                                      const unsigned short* __restrict__ Wbf,
                                                      unsigned short* __restrict__ Qbf,
                                                      unsigned short* __restrict__ Kbf,
                                                      unsigned short* __restrict__ Vbf) {
    __shared__ __align__(16) unsigned short A[64][264];
    __shared__ __align__(16) unsigned short Ost[2][32][136];
    const int tid = threadIdx.x;
    const int b = blockIdx.x & 7;
    const int qt = (blockIdx.x >> 3) << 6;
    const float* lb = l + ((size_t)b * NC * NHW + qt);

    for (int s = 0; s < 16; ++s) {
        int f = tid + s * 256;
        int c = f >> 4, j = f & 15;
        float4 v = *(const float4*)(lb + (size_t)c * NHW + j * 4);
        ushort4 o4;
        o4.x = f2bf(v.x); o4.y = f2bf(v.y); o4.z = f2bf(v.z); o4.w = f2bf(v.w);
        A[j * 4 + 0][c] = o4.x;
        A[j * 4 + 1][c] = o4.y;
        A[j * 4 + 2][c] = o4.z;
        A[j * 4 + 3][c] = o4.w;
        *(ushort4*)(Vbf + (size_t)b * NC * NHW + (size_t)c * NHW + qt + j * 4) = o4;
    }
    __syncthreads();

    const int w = tid >> 6, L = tid & 63;
    const int l15 = L & 15, q4 = L >> 4;
    const v4f vz = {0.f, 0.f, 0.f, 0.f};
    v4f acc[4][4];
    for (int mt = 0; mt < 4; ++mt)
        for (int nt = 0; nt < 4; ++nt) acc[mt][nt] = vz;

    for (int kf = 0; kf < 8; ++kf) {
        int kc = kf * 32 + q4 * 8;
        v8bf a[4], bb[4];
        for (int mt = 0; mt < 4; ++mt)
            a[mt] = *(const v8bf*)&A[mt * 16 + l15][kc];
        for (int nt = 0; nt < 4; ++nt)
            bb[nt] = *(const v8bf*)(Wbf + (w * 64 + nt * 16 + l15) * 256 + kc);
        for (int mt = 0; mt < 4; ++mt)
            for (int nt = 0; nt < 4; ++nt)
                acc[mt][nt] = __builtin_amdgcn_mfma_f32_16x16x32_bf16(a[mt], bb[nt], acc[mt][nt], 0, 0, 0);
    }

    const int side = w >> 1;
    const int ebase = (w & 1) * 64;
#pragma unroll
    for (int ph = 0; ph < 2; ++ph) {
        __syncthreads();
#pragma unroll
        for (int mh = 0; mh < 2; ++mh) {
            int mt = ph * 2 + mh;
#pragma unroll
            for (int nt = 0; nt < 4; ++nt)
#pragma unroll
                for (int r = 0; r < 4; ++r) {
                    int q32 = mh * 16 + q4 * 4 + r;
                    Ost[side][q32][ebase + nt * 16 + l15] = f2bf(acc[mt][nt][r]);
                }
        }
        __syncthreads();
#pragma unroll
        for (int s = 0; s < 4; ++s) {
            int idx = tid + s * 256;
            int sd = idx >> 9, rem = idx & 511;
            int r32 = rem >> 4, c8 = rem & 15;
            unsigned short* dst = sd ? Kbf : Qbf;
            int c8s = sd ? (c8 ^ (r32 & 15)) : c8;   // pre-swizzle K only
            *(uint4*)(dst + ((size_t)b * NHW + qt + ph * 32 + r32) * NE + c8s * 8) =
                *(const uint4*)&Ost[sd][r32][c8 * 8];
        }
    }
}

// ---------------- K2: flash attention, SPLIT-LOOP producer/consumer wave
// specialization (R8 structure: liveness-decoupled P/C regions, VGPR 96, zero
// spill) + R9 direct-scatter P^T writes.
// R10: K-TILE 128 -> 33 rounds instead of 65.  Round time was ~4230 cyc vs
// 1536 cyc of per-SIMD matrix demand; the gap includes a large per-round fixed
// cost (barrier skew, drains, jitter-max over 8 waves).  Halving round count
// halves that total: 64(W+O) -> 32(2W+O) saves 32*O.  Also: softmax is now
// textually FIRST, with QK(i+1) writing s_prev directly (anti-dependency
// replaces the 32-mov s_prev<-s_new copy).  Per-accumulator K-order and all
// lacc summation order bit-identical to R9.
// Barrier audit: both regions execute 2 prologue + 33 loop + 1 epilogue = 36.
// Parity: P writes Pu[it&1], C reads Pu[(it-1)&1]; QK(i+1) reads Ku[(i+1)&1],
// DMA(i+2) fills Ku[i&1] -- isomorphic to the audited R8/R9 schedule.
// C loads V in halves: av (kf0-3, loaded prev iter) + av2 (kf4-7, issued at
// iter start, consumed after ~1000 cyc of first-half MFMA) -> peak ~220 regs.
// LDS: Ku dbuf 64K | Pu dbuf 64K | lsum 512B = 131584 B (1 block/CU; HW cap 160K).
__global__ __launch_bounds__(512, 2) void attn_kernel(const unsigned short* __restrict__ Qbf,
                                                      const unsigned short* __restrict__ Kbf,
                                                      const unsigned short* __restrict__ Vbf,
                                                      float* __restrict__ out) {
    __shared__ __align__(16) unsigned char smem[131584];
    unsigned short* KuS = (unsigned short*)smem;             // 2 x 32KB, swizzled tiles
    unsigned short* PuS = (unsigned short*)(smem + 65536);   // 2 x 32 frag-tiles x 1KB
    float* lsumF = (float*)(smem + 131072);                  // [4][32]

    const int tid = threadIdx.x;
    const int b = blockIdx.x & 7;                            // batch -> XCD affinity
    const int q128 = (blockIdx.x >> 3) << 7;
    const int w = tid >> 6;                                  // wave 0-7 -> SIMD w&3
    const int L = tid & 63;
    const int l31 = L & 31, hi = L >> 5;
    const int x15 = l31 & 15;

    const unsigned short* Kb = Kbf + (size_t)b * NHW * NE;
    const unsigned short* Vb = Vbf + (size_t)b * NC * NHW;

    if (w < 4) {
        // ==================== PRODUCER region ====================
        float lacc = 0.f;
        v8bf bq[8];
        const unsigned short* qrow = Qbf + ((size_t)b * NHW + q128 + w * 32 + l31) * NE + hi * 8;
#pragma unroll
        for (int ef = 0; ef < 8; ++ef)
            bq[ef] = *(const v8bf*)(qrow + ef * 16);
        // prologue A: DMA K tile 0 (128 rows = 32 chunks, 8/wave) -> buf 0
#pragma unroll
        for (int jj = 0; jj < 8; ++jj) {
            int j = w * 8 + jj;
            dma16(Kb + (size_t)j * 512 + L * 8, KuS + j * 512);
        }
        WAIT_VM0();
        BARRIER_LDS();                                       // barrier #1
        // prologue B: DMA K tile 1 -> buf 1; QK(0) -> s_prev
#pragma unroll
        for (int jj = 0; jj < 8; ++jj) {
            int j = w * 8 + jj;
            dma16(Kb + (size_t)16384 + j * 512 + L * 8, KuS + 16384 + j * 512);
        }
        v16f s_prev[4];
        {
            const unsigned short* kub = KuS;
#pragma unroll
            for (int kt = 0; kt < 4; ++kt) {
                v16f sa, sb;
#pragma unroll
                for (int r = 0; r < 16; ++r) { sa[r] = 0.f; sb[r] = 0.f; }
                const unsigned short* krow = kub + (kt * 32 + l31) * 128;
#pragma unroll
                for (int ef = 0; ef < 4; ++ef) {
                    v8bf ak0 = *(const v8bf*)(krow + (((2 * ef + hi) ^ x15) * 8));
                    v8bf ak1 = *(const v8bf*)(krow + (((2 * (ef + 4) + hi) ^ x15) * 8));
                    sa = __builtin_amdgcn_mfma_f32_32x32x16_bf16(ak0, bq[ef], sa, 0, 0, 0);
                    sb = __builtin_amdgcn_mfma_f32_32x32x16_bf16(ak1, bq[ef + 4], sb, 0, 0, 0);
                }
#pragma unroll
                for (int r = 0; r < 16; ++r) s_prev[kt][r] = sa[r] + sb[r];
            }
        }
        WAIT_VM0();                                          // DMA(1) landed
        BARRIER_LDS();                                       // barrier #2

        // scatter-write address components (loop-invariant; R9-verified image)
        const int a1 = l31 * 8 + hi * 4;                     // shorts: unit l31, word-half hi
        const int a2 = (l31 + 32) * 8 + hi * 4;              // shorts: unit l31+32, word-half hi

        for (int it = 0; it < 33; ++it) {
            if (it < 32) {
                const int buf = it & 1;                      // Pu publish buf; DMA(i+2) Ku buf
                if (it <= 29) {
                    // DMA K(i+2) into Ku buf[(i+2)&1] = buf[i&1] (tile i dead: QK'd last iter)
                    const size_t kro = (size_t)(it + 2) * 16384;   // shorts: tile*128rows*128
#pragma unroll
                    for (int jj = 0; jj < 8; ++jj) {
                        int j = w * 8 + jj;
                        dma16(Kb + kro + j * 512 + L * 8, KuS + buf * 16384 + j * 512);
                    }
                }
                // softmax(i) from s_prev -> scatter into Pu[buf]
#pragma unroll
                for (int kt = 0; kt < 4; ++kt) {
                    float p[16];
#pragma unroll
                    for (int r = 0; r < 16; ++r) p[r] = EXP2F(s_prev[kt][r]);
                    {   // row-sum: depth-4 tree (R9-verified)
                        float t0 = (p[0] + p[1]) + (p[2] + p[3]);
                        float t1 = (p[4] + p[5]) + (p[6] + p[7]);
                        float t2 = (p[8] + p[9]) + (p[10] + p[11]);
                        float t3 = (p[12] + p[13]) + (p[14] + p[15]);
                        lacc += (t0 + t1) + (t2 + t3);
                    }
                    unsigned int pk[8];
#pragma unroll
                    for (int t = 0; t < 8; ++t) pk[t] = pack_bf2_ru(p[2 * t], p[2 * t + 1]);
                    unsigned short* base0 = PuS + buf * 16384 + (w * 8 + kt * 2) * 512;
                    *(v2u*)(base0 + a1)       = (v2u){pk[0], pk[1]};
                    *(v2u*)(base0 + a2)       = (v2u){pk[2], pk[3]};
                    *(v2u*)(base0 + 512 + a1) = (v2u){pk[4], pk[5]};
                    *(v2u*)(base0 + 512 + a2) = (v2u){pk[6], pk[7]};
                }
                // QK(i+1) -> s_prev (direct overwrite; anti-dep replaces the copy)
                if (it <= 30) {
                    const unsigned short* kub = KuS + ((it + 1) & 1) * 16384;
#pragma unroll
                    for (int kt = 0; kt < 4; ++kt) {
                        v16f sa, sb;
#pragma unroll
                        for (int r = 0; r < 16; ++r) { sa[r] = 0.f; sb[r] = 0.f; }
                        const unsigned short* krow = kub + (kt * 32 + l31) * 128;
#pragma unroll
                        for (int ef = 0; ef < 4; ++ef) {
                            v8bf ak0 = *(const v8bf*)(krow + (((2 * ef + hi) ^ x15) * 8));
                            v8bf ak1 = *(const v8bf*)(krow + (((2 * (ef + 4) + hi) ^ x15) * 8));
                            sa = __builtin_amdgcn_mfma_f32_32x32x16_bf16(ak0, bq[ef], sa, 0, 0, 0);
                            sb = __builtin_amdgcn_mfma_f32_32x32x16_bf16(ak1, bq[ef + 4], sb, 0, 0, 0);
                        }
#pragma unroll
                        for (int r = 0; r < 16; ++r) s_prev[kt][r] = sa[r] + sb[r];
                    }
                }
                WAIT_VM0();                                  // DMA(i+2) landed before barrier
            }
            BARRIER_LDS();                                   // barriers #3..#35
        }
        // epilogue: row-sum handoff
        float tot = lacc + __shfl_xor(lacc, 32);
        if (hi == 0) lsumF[w * 32 + l31] = tot;
        BARRIER_LDS();                                       // barrier #36
    } else {
        // ==================== CONSUMER region ====================
        const int ci = w - 4;
        v16f o[2][4];                                        // acc [ct][qt], 128 regs
#pragma unroll
        for (int ct = 0; ct < 2; ++ct)
#pragma unroll
            for (int qt = 0; qt < 4; ++qt)
#pragma unroll
                for (int r = 0; r < 16; ++r) o[ct][qt][r] = 0.f;
        const unsigned short* vb0 = Vb + (size_t)(ci * 64 + l31) * NHW + hi * 8;
        const unsigned short* vb1 = Vb + (size_t)(ci * 64 + 32 + l31) * NHW + hi * 8;
        v8bf av[2][4];                                       // kf0-3 of next PV tile
#pragma unroll
        for (int kf = 0; kf < 4; ++kf) {
            av[0][kf] = *(const v8bf*)(vb0 + kf * 16);
            av[1][kf] = *(const v8bf*)(vb1 + kf * 16);
        }
        BARRIER_LDS();                                       // barrier #1
        BARRIER_LDS();                                       // barrier #2 (P prologue B window)

        for (int it = 0; it < 33; ++it) {
            if (it > 0) {
                // issue kf4-7 V frags of tile it-1 early (landed under first-half MFMAs)
                const size_t kcA = (size_t)(it - 1) * 128;
                v8bf av2[2][4];
#pragma unroll
                for (int kf = 0; kf < 4; ++kf) {
                    av2[0][kf] = *(const v8bf*)(vb0 + kcA + (kf + 4) * 16);
                    av2[1][kf] = *(const v8bf*)(vb1 + kcA + (kf + 4) * 16);
                }
                const int pbuf = (it - 1) & 1;
                const unsigned short* pb = PuS + pbuf * 16384 + (hi * 32 + l31) * 8;
                // first half: kf 0-3 (av, preloaded last iter)
#pragma unroll
                for (int qt = 0; qt < 4; ++qt) {
                    v8bf bp[4];
#pragma unroll
                    for (int kf = 0; kf < 4; ++kf)
                        bp[kf] = *(const v8bf*)(pb + (qt * 8 + kf) * 512);
#pragma unroll
                    for (int kf = 0; kf < 4; ++kf) {
                        o[0][qt] = __builtin_amdgcn_mfma_f32_32x32x16_bf16(av[0][kf], bp[kf], o[0][qt], 0, 0, 0);
                        o[1][qt] = __builtin_amdgcn_mfma_f32_32x32x16_bf16(av[1][kf], bp[kf], o[1][qt], 0, 0, 0);
                    }
                }
                // second half: kf 4-7 (av2)
#pragma unroll
                for (int qt = 0; qt < 4; ++qt) {
                    v8bf bp[4];
#pragma unroll
                    for (int kf = 0; kf < 4; ++kf)
                        bp[kf] = *(const v8bf*)(pb + (qt * 8 + 4 + kf) * 512);
#pragma unroll
                    for (int kf = 0; kf < 4; ++kf) {
                        o[0][qt] = __builtin_amdgcn_mfma_f32_32x32x16_bf16(av2[0][kf], bp[kf], o[0][qt], 0, 0, 0);
                        o[1][qt] = __builtin_amdgcn_mfma_f32_32x32x16_bf16(av2[1][kf], bp[kf], o[1][qt], 0, 0, 0);
                    }
                }
                // preload kf0-3 of tile it (wrapped at it=32: dead uniform load)
                const size_t kcB = (size_t)(it & 31) * 128;
#pragma unroll
                for (int kf = 0; kf < 4; ++kf) {
                    av[0][kf] = *(const v8bf*)(vb0 + kcB + kf * 16);
                    av[1][kf] = *(const v8bf*)(vb1 + kcB + kf * 16);
                }
            }
            BARRIER_LDS();                                   // barriers #3..#35
        }
        BARRIER_LDS();                                       // barrier #36 (lsum ready)
        float inv[4];
#pragma unroll
        for (int qt = 0; qt < 4; ++qt) inv[qt] = 1.0f / lsumF[qt * 32 + l31];
        // store: O^T C/D lane = q-col -> coalesced dwords
#pragma unroll
        for (int ct = 0; ct < 2; ++ct)
#pragma unroll
            for (int qt = 0; qt < 4; ++qt) {
                float* ob = out + (size_t)b * NC * NHW + q128 + qt * 32 + l31;
#pragma unroll
                for (int r = 0; r < 16; ++r) {
                    int c = ci * 64 + ct * 32 + (r & 3) + 8 * (r >> 2) + 4 * hi;
                    ob[(size_t)c * NHW] = o[ct][qt][r] * inv[qt];
                }
            }
    }
}

extern "C" void kernel_launch(void* const* d_in, const int* in_sizes, int n_in,
                              void* d_out, int out_size, void* d_ws, size_t ws_size,
                              hipStream_t stream) {
    const float* l  = (const float*)d_in[0];
    const float* wt = (const float*)d_in[1];
    const float* wp = (const float*)d_in[2];
    float* out = (float*)d_out;

    char* ws = (char*)d_ws;
    unsigned short* Wbf = (unsigned short*)ws;                          // 131072 B
    unsigned short* Qbf = (unsigned short*)(ws + 131072);               // 8 MB
    unsigned short* Kbf = (unsigned short*)(ws + 131072 + 8388608);     // 8 MB (pre-swizzled)
    unsigned short* Vbf = (unsigned short*)(ws + 131072 + 16777216);    // 16 MB

    hipLaunchKernelGGL(cast_w_kernel, dim3(256), dim3(256), 0, stream, wt, wp, Wbf);
    hipLaunchKernelGGL(proj_kernel,   dim3(512), dim3(256), 0, stream, l, Wbf, Qbf, Kbf, Vbf);
    hipLaunchKernelGGL(attn_kernel,   dim3(256), dim3(512), 0, stream, Qbf, Kbf, Vbf, out);
}

// Round 11
// 194.182 us; speedup vs baseline: 2.1695x; 1.0190x over previous
//
#include <hip/hip_runtime.h>
#include <stdint.h>

#define NB 8
#define NC 256
#define NE 128
#define NHW 4096

typedef __bf16 v8bf __attribute__((ext_vector_type(8)));
typedef float v4f __attribute__((ext_vector_type(4)));
typedef float v16f __attribute__((ext_vector_type(16)));
typedef unsigned int v4u __attribute__((ext_vector_type(4)));
typedef unsigned int v2u __attribute__((ext_vector_type(2)));

typedef unsigned int __attribute__((address_space(1))) uint_g;
typedef unsigned int __attribute__((address_space(3))) uint_l;

#if __has_builtin(__builtin_amdgcn_exp2f)
#define EXP2F(x) __builtin_amdgcn_exp2f(x)
#else
#define EXP2F(x) exp2f(x)
#endif

// LDS-only barrier: drains lgkmcnt but NOT vmcnt (global prefetch/DMA stays in flight)
#define BARRIER_LDS() asm volatile("s_waitcnt lgkmcnt(0)\n\ts_barrier" ::: "memory")
#define WAIT_VM0()    asm volatile("s_waitcnt vmcnt(0)" ::: "memory")

// async global->LDS DMA, 16B per lane: LDS dst = uniform base + lane*16
__device__ __forceinline__ void dma16(const unsigned short* g, unsigned short* l) {
    __builtin_amdgcn_global_load_lds((const uint_g*)g, (uint_l*)l, 16, 0, 0);
}

// fp32 -> bf16 round-to-nearest-even
__device__ __forceinline__ unsigned short f2bf(float x) {
    union { float f; unsigned int u; } v; v.f = x;
    unsigned int r = v.u + 0x7fffu + ((v.u >> 16) & 1u);
    return (unsigned short)(r >> 16);
}

// pack two fp32 -> bf16x2, round-half-up (P in (0,1], R4-verified accuracy)
__device__ __forceinline__ unsigned int pack_bf2_ru(float a, float b) {
    union { float f; unsigned int u; } va, vb; va.f = a; vb.f = b;
    return ((va.u + 0x8000u) >> 16) | ((vb.u + 0x8000u) & 0xffff0000u);
}

// ---------------- K0: cast weights. Wbf[e][c], e<128 = w_theta*(scale*log2e), e>=128 = w_phi
__global__ __launch_bounds__(256) void cast_w_kernel(const float* __restrict__ wt,
                                                     const float* __restrict__ wp,
                                                     unsigned short* __restrict__ Wbf) {
    int i = blockIdx.x * 256 + threadIdx.x;
    const float QS = 0.08838834764831845f * 1.4426950408889634f;
    float v = (i < 32768) ? wt[i] * QS : wp[i - 32768];
    Wbf[i] = f2bf(v);
}

// ---------------- K1: projection (+ fused V cast). K is stored PRE-SWIZZLED
// (16B unit u at position u ^ (row&15) within each row) so attn's LDS DMA copy
// is read conflict-free with the R5-verified fragment pattern. Q unswizzled.
// R0-exact form (R6's 32-tile variant regressed: W re-read doubling).
__global__ __launch_bounds__(256, 2) void proj_kernel(const float* __restrict__ l,
                                                      const unsigned short* __restrict__ Wbf,
                                                      unsigned short* __restrict__ Qbf,
                                                      unsigned short* __restrict__ Kbf,
                                                      unsigned short* __restrict__ Vbf) {
    __shared__ __align__(16) unsigned short A[64][264];
    __shared__ __align__(16) unsigned short Ost[2][32][136];
    const int tid = threadIdx.x;
    const int b = blockIdx.x & 7;
    const int qt = (blockIdx.x >> 3) << 6;
    const float* lb = l + ((size_t)b * NC * NHW + qt);

    for (int s = 0; s < 16; ++s) {
        int f = tid + s * 256;
        int c = f >> 4, j = f & 15;
        float4 v = *(const float4*)(lb + (size_t)c * NHW + j * 4);
        ushort4 o4;
        o4.x = f2bf(v.x); o4.y = f2bf(v.y); o4.z = f2bf(v.z); o4.w = f2bf(v.w);
        A[j * 4 + 0][c] = o4.x;
        A[j * 4 + 1][c] = o4.y;
        A[j * 4 + 2][c] = o4.z;
        A[j * 4 + 3][c] = o4.w;
        *(ushort4*)(Vbf + (size_t)b * NC * NHW + (size_t)c * NHW + qt + j * 4) = o4;
    }
    __syncthreads();

    const int w = tid >> 6, L = tid & 63;
    const int l15 = L & 15, q4 = L >> 4;
    const v4f vz = {0.f, 0.f, 0.f, 0.f};
    v4f acc[4][4];
    for (int mt = 0; mt < 4; ++mt)
        for (int nt = 0; nt < 4; ++nt) acc[mt][nt] = vz;

    for (int kf = 0; kf < 8; ++kf) {
        int kc = kf * 32 + q4 * 8;
        v8bf a[4], bb[4];
        for (int mt = 0; mt < 4; ++mt)
            a[mt] = *(const v8bf*)&A[mt * 16 + l15][kc];
        for (int nt = 0; nt < 4; ++nt)
            bb[nt] = *(const v8bf*)(Wbf + (w * 64 + nt * 16 + l15) * 256 + kc);
        for (int mt = 0; mt < 4; ++mt)
            for (int nt = 0; nt < 4; ++nt)
                acc[mt][nt] = __builtin_amdgcn_mfma_f32_16x16x32_bf16(a[mt], bb[nt], acc[mt][nt], 0, 0, 0);
    }

    const int side = w >> 1;
    const int ebase = (w & 1) * 64;
#pragma unroll
    for (int ph = 0; ph < 2; ++ph) {
        __syncthreads();
#pragma unroll
        for (int mh = 0; mh < 2; ++mh) {
            int mt = ph * 2 + mh;
#pragma unroll
            for (int nt = 0; nt < 4; ++nt)
#pragma unroll
                for (int r = 0; r < 4; ++r) {
                    int q32 = mh * 16 + q4 * 4 + r;
                    Ost[side][q32][ebase + nt * 16 + l15] = f2bf(acc[mt][nt][r]);
                }
        }
        __syncthreads();
#pragma unroll
        for (int s = 0; s < 4; ++s) {
            int idx = tid + s * 256;
            int sd = idx >> 9, rem = idx & 511;
            int r32 = rem >> 4, c8 = rem & 15;
            unsigned short* dst = sd ? Kbf : Qbf;
            int c8s = sd ? (c8 ^ (r32 & 15)) : c8;   // pre-swizzle K only
            *(uint4*)(dst + ((size_t)b * NHW + qt + ph * 32 + r32) * NE + c8s * 8) =
                *(const uint4*)&Ost[sd][r32][c8 * 8];
        }
    }
}

// ---------------- K2: flash attention, SPLIT-LOOP producer/consumer wave
// specialization (R8 structure) + R9 direct-scatter + R10 k-tile 128.
// R11: ACCUMULATOR-CHAIN INTERLEAVE.  R10 post-mortem: round time scales
// ~linearly with MFMA work at ~40% util -> binding constraint is same-
// accumulator MFMA dependency latency (only 2 chains in flight: qt-major C
// order, kt-major P order).  Reorder MFMA issue so 8 INDEPENDENT accumulator
// chains interleave (reuse distance 2 -> 8 issues):
//  - C: kf-major.  Per kf: 4 bp ds_reads, then 8 MFMAs across o[0..1][0..3].
//    Per-accumulator kf-order unchanged (kf0..7) -> bit-identical; zero reg delta.
//  - P: ef-major across all 4 kt.  ef0-3 half accumulates DIRECTLY into
//    s_prev[kt] (dead after softmax -> free accumulator), ef4-7 into tmp[kt];
//    final s_prev += tmp.  Per-chain order identical to R10's sa/sb + add ->
//    bit-identical.  tmp = +64 transient regs; P peak ~200 < 256.
// All else (DMA schedule, parities, barriers [36/36], scatter image, epilogue)
// identical to R10.  No setprio (R7: -8%).
// LDS: Ku dbuf 64K | Pu dbuf 64K | lsum 512B = 131584 B (1 block/CU).
__global__ __launch_bounds__(512, 2) void attn_kernel(const unsigned short* __restrict__ Qbf,
                                                      const unsigned short* __restrict__ Kbf,
                                                      const unsigned short* __restrict__ Vbf,
                                                      float* __restrict__ out) {
    __shared__ __align__(16) unsigned char smem[131584];
    unsigned short* KuS = (unsigned short*)smem;             // 2 x 32KB, swizzled tiles
    unsigned short* PuS = (unsigned short*)(smem + 65536);   // 2 x 32 frag-tiles x 1KB
    float* lsumF = (float*)(smem + 131072);                  // [4][32]

    const int tid = threadIdx.x;
    const int b = blockIdx.x & 7;                            // batch -> XCD affinity
    const int q128 = (blockIdx.x >> 3) << 7;
    const int w = tid >> 6;                                  // wave 0-7 -> SIMD w&3
    const int L = tid & 63;
    const int l31 = L & 31, hi = L >> 5;
    const int x15 = l31 & 15;

    const unsigned short* Kb = Kbf + (size_t)b * NHW * NE;
    const unsigned short* Vb = Vbf + (size_t)b * NC * NHW;

    if (w < 4) {
        // ==================== PRODUCER region ====================
        float lacc = 0.f;
        v8bf bq[8];
        const unsigned short* qrow = Qbf + ((size_t)b * NHW + q128 + w * 32 + l31) * NE + hi * 8;
#pragma unroll
        for (int ef = 0; ef < 8; ++ef)
            bq[ef] = *(const v8bf*)(qrow + ef * 16);
        // prologue A: DMA K tile 0 (128 rows = 32 chunks, 8/wave) -> buf 0
#pragma unroll
        for (int jj = 0; jj < 8; ++jj) {
            int j = w * 8 + jj;
            dma16(Kb + (size_t)j * 512 + L * 8, KuS + j * 512);
        }
        WAIT_VM0();
        BARRIER_LDS();                                       // barrier #1
        // prologue B: DMA K tile 1 -> buf 1; QK(0) -> s_prev (8-chain interleave)
#pragma unroll
        for (int jj = 0; jj < 8; ++jj) {
            int j = w * 8 + jj;
            dma16(Kb + (size_t)16384 + j * 512 + L * 8, KuS + 16384 + j * 512);
        }
        v16f s_prev[4];
        {
            v16f tmp[4];
#pragma unroll
            for (int kt = 0; kt < 4; ++kt)
#pragma unroll
                for (int r = 0; r < 16; ++r) { s_prev[kt][r] = 0.f; tmp[kt][r] = 0.f; }
#pragma unroll
            for (int ef = 0; ef < 4; ++ef)
#pragma unroll
                for (int kt = 0; kt < 4; ++kt) {
                    const unsigned short* krow = KuS + (kt * 32 + l31) * 128;
                    v8bf ak0 = *(const v8bf*)(krow + (((2 * ef + hi) ^ x15) * 8));
                    v8bf ak1 = *(const v8bf*)(krow + (((2 * (ef + 4) + hi) ^ x15) * 8));
                    s_prev[kt] = __builtin_amdgcn_mfma_f32_32x32x16_bf16(ak0, bq[ef], s_prev[kt], 0, 0, 0);
                    tmp[kt]    = __builtin_amdgcn_mfma_f32_32x32x16_bf16(ak1, bq[ef + 4], tmp[kt], 0, 0, 0);
                }
#pragma unroll
            for (int kt = 0; kt < 4; ++kt)
#pragma unroll
                for (int r = 0; r < 16; ++r) s_prev[kt][r] += tmp[kt][r];
        }
        WAIT_VM0();                                          // DMA(1) landed
        BARRIER_LDS();                                       // barrier #2

        // scatter-write address components (loop-invariant; R9-verified image)
        const int a1 = l31 * 8 + hi * 4;                     // shorts: unit l31, word-half hi
        const int a2 = (l31 + 32) * 8 + hi * 4;              // shorts: unit l31+32, word-half hi

        for (int it = 0; it < 33; ++it) {
            if (it < 32) {
                const int buf = it & 1;                      // Pu publish buf; DMA(i+2) Ku buf
                if (it <= 29) {
                    // DMA K(i+2) into Ku buf[(i+2)&1] = buf[i&1] (tile i dead: QK'd last iter)
                    const size_t kro = (size_t)(it + 2) * 16384;   // shorts: tile*128rows*128
#pragma unroll
                    for (int jj = 0; jj < 8; ++jj) {
                        int j = w * 8 + jj;
                        dma16(Kb + kro + j * 512 + L * 8, KuS + buf * 16384 + j * 512);
                    }
                }
                // softmax(i) from s_prev -> scatter into Pu[buf]
#pragma unroll
                for (int kt = 0; kt < 4; ++kt) {
                    float p[16];
#pragma unroll
                    for (int r = 0; r < 16; ++r) p[r] = EXP2F(s_prev[kt][r]);
                    {   // row-sum: depth-4 tree (R9-verified)
                        float t0 = (p[0] + p[1]) + (p[2] + p[3]);
                        float t1 = (p[4] + p[5]) + (p[6] + p[7]);
                        float t2 = (p[8] + p[9]) + (p[10] + p[11]);
                        float t3 = (p[12] + p[13]) + (p[14] + p[15]);
                        lacc += (t0 + t1) + (t2 + t3);
                    }
                    unsigned int pk[8];
#pragma unroll
                    for (int t = 0; t < 8; ++t) pk[t] = pack_bf2_ru(p[2 * t], p[2 * t + 1]);
                    unsigned short* base0 = PuS + buf * 16384 + (w * 8 + kt * 2) * 512;
                    *(v2u*)(base0 + a1)       = (v2u){pk[0], pk[1]};
                    *(v2u*)(base0 + a2)       = (v2u){pk[2], pk[3]};
                    *(v2u*)(base0 + 512 + a1) = (v2u){pk[4], pk[5]};
                    *(v2u*)(base0 + 512 + a2) = (v2u){pk[6], pk[7]};
                }
                // QK(i+1) -> s_prev (direct accumulate; 8 chains in flight)
                if (it <= 30) {
                    const unsigned short* kub = KuS + ((it + 1) & 1) * 16384;
                    v16f tmp[4];
#pragma unroll
                    for (int kt = 0; kt < 4; ++kt)
#pragma unroll
                        for (int r = 0; r < 16; ++r) { s_prev[kt][r] = 0.f; tmp[kt][r] = 0.f; }
#pragma unroll
                    for (int ef = 0; ef < 4; ++ef)
#pragma unroll
                        for (int kt = 0; kt < 4; ++kt) {
                            const unsigned short* krow = kub + (kt * 32 + l31) * 128;
                            v8bf ak0 = *(const v8bf*)(krow + (((2 * ef + hi) ^ x15) * 8));
                            v8bf ak1 = *(const v8bf*)(krow + (((2 * (ef + 4) + hi) ^ x15) * 8));
                            s_prev[kt] = __builtin_amdgcn_mfma_f32_32x32x16_bf16(ak0, bq[ef], s_prev[kt], 0, 0, 0);
                            tmp[kt]    = __builtin_amdgcn_mfma_f32_32x32x16_bf16(ak1, bq[ef + 4], tmp[kt], 0, 0, 0);
                        }
#pragma unroll
                    for (int kt = 0; kt < 4; ++kt)
#pragma unroll
                        for (int r = 0; r < 16; ++r) s_prev[kt][r] += tmp[kt][r];
                }
                WAIT_VM0();                                  // DMA(i+2) landed before barrier
            }
            BARRIER_LDS();                                   // barriers #3..#35
        }
        // epilogue: row-sum handoff
        float tot = lacc + __shfl_xor(lacc, 32);
        if (hi == 0) lsumF[w * 32 + l31] = tot;
        BARRIER_LDS();                                       // barrier #36
    } else {
        // ==================== CONSUMER region ====================
        const int ci = w - 4;
        v16f o[2][4];                                        // acc [ct][qt], 128 regs
#pragma unroll
        for (int ct = 0; ct < 2; ++ct)
#pragma unroll
            for (int qt = 0; qt < 4; ++qt)
#pragma unroll
                for (int r = 0; r < 16; ++r) o[ct][qt][r] = 0.f;
        const unsigned short* vb0 = Vb + (size_t)(ci * 64 + l31) * NHW + hi * 8;
        const unsigned short* vb1 = Vb + (size_t)(ci * 64 + 32 + l31) * NHW + hi * 8;
        v8bf av[2][4];                                       // kf0-3 of next PV tile
#pragma unroll
        for (int kf = 0; kf < 4; ++kf) {
            av[0][kf] = *(const v8bf*)(vb0 + kf * 16);
            av[1][kf] = *(const v8bf*)(vb1 + kf * 16);
        }
        BARRIER_LDS();                                       // barrier #1
        BARRIER_LDS();                                       // barrier #2 (P prologue B window)

        for (int it = 0; it < 33; ++it) {
            if (it > 0) {
                // issue kf4-7 V frags of tile it-1 early (landed under first-half MFMAs)
                const size_t kcA = (size_t)(it - 1) * 128;
                v8bf av2[2][4];
#pragma unroll
                for (int kf = 0; kf < 4; ++kf) {
                    av2[0][kf] = *(const v8bf*)(vb0 + kcA + (kf + 4) * 16);
                    av2[1][kf] = *(const v8bf*)(vb1 + kcA + (kf + 4) * 16);
                }
                const int pbuf = (it - 1) & 1;
                const unsigned short* pb = PuS + pbuf * 16384 + (hi * 32 + l31) * 8;
                // kf-major: per kf, 4 bp reads then 8 MFMAs across all 8 accumulators
#pragma unroll
                for (int kf = 0; kf < 4; ++kf) {
                    v8bf bp[4];
#pragma unroll
                    for (int qt = 0; qt < 4; ++qt)
                        bp[qt] = *(const v8bf*)(pb + (qt * 8 + kf) * 512);
#pragma unroll
                    for (int qt = 0; qt < 4; ++qt) {
                        o[0][qt] = __builtin_amdgcn_mfma_f32_32x32x16_bf16(av[0][kf], bp[qt], o[0][qt], 0, 0, 0);
                        o[1][qt] = __builtin_amdgcn_mfma_f32_32x32x16_bf16(av[1][kf], bp[qt], o[1][qt], 0, 0, 0);
                    }
                }
#pragma unroll
                for (int kf = 0; kf < 4; ++kf) {
                    v8bf bp[4];
#pragma unroll
                    for (int qt = 0; qt < 4; ++qt)
                        bp[qt] = *(const v8bf*)(pb + (qt * 8 + 4 + kf) * 512);
#pragma unroll
                    for (int qt = 0; qt < 4; ++qt) {
                        o[0][qt] = __builtin_amdgcn_mfma_f32_32x32x16_bf16(av2[0][kf], bp[qt], o[0][qt], 0, 0, 0);
                        o[1][qt] = __builtin_amdgcn_mfma_f32_32x32x16_bf16(av2[1][kf], bp[qt], o[1][qt], 0, 0, 0);
                    }
                }
                // preload kf0-3 of tile it (wrapped at it=32: dead uniform load)
                const size_t kcB = (size_t)(it & 31) * 128;
#pragma unroll
                for (int kf = 0; kf < 4; ++kf) {
                    av[0][kf] = *(const v8bf*)(vb0 + kcB + kf * 16);
                    av[1][kf] = *(const v8bf*)(vb1 + kcB + kf * 16);
                }
            }
            BARRIER_LDS();                                   // barriers #3..#35
        }
        BARRIER_LDS();                                       // barrier #36 (lsum ready)
        float inv[4];
#pragma unroll
        for (int qt = 0; qt < 4; ++qt) inv[qt] = 1.0f / lsumF[qt * 32 + l31];
        // store: O^T C/D lane = q-col -> coalesced dwords
#pragma unroll
        for (int ct = 0; ct < 2; ++ct)
#pragma unroll
            for (int qt = 0; qt < 4; ++qt) {
                float* ob = out + (size_t)b * NC * NHW + q128 + qt * 32 + l31;
#pragma unroll
                for (int r = 0; r < 16; ++r) {
                    int c = ci * 64 + ct * 32 + (r & 3) + 8 * (r >> 2) + 4 * hi;
                    ob[(size_t)c * NHW] = o[ct][qt][r] * inv[qt];
                }
            }
    }
}

extern "C" void kernel_launch(void* const* d_in, const int* in_sizes, int n_in,
                              void* d_out, int out_size, void* d_ws, size_t ws_size,
                              hipStream_t stream) {
    const float* l  = (const float*)d_in[0];
    const float* wt = (const float*)d_in[1];
    const float* wp = (const float*)d_in[2];
    float* out = (float*)d_out;

    char* ws = (char*)d_ws;
    unsigned short* Wbf = (unsigned short*)ws;                          // 131072 B
    unsigned short* Qbf = (unsigned short*)(ws + 131072);               // 8 MB
    unsigned short* Kbf = (unsigned short*)(ws + 131072 + 8388608);     // 8 MB (pre-swizzled)
    unsigned short* Vbf = (unsigned short*)(ws + 131072 + 16777216);    // 16 MB

    hipLaunchKernelGGL(cast_w_kernel, dim3(256), dim3(256), 0, stream, wt, wp, Wbf);
    hipLaunchKernelGGL(proj_kernel,   dim3(512), dim3(256), 0, stream, l, Wbf, Qbf, Kbf, Vbf);
    hipLaunchKernelGGL(attn_kernel,   dim3(256), dim3(512), 0, stream, Qbf, Kbf, Vbf, out);
}